// Round 1
// baseline (902.408 us; speedup 1.0000x reference)
//
#include <hip/hip_runtime.h>
#include <hip/hip_bf16.h>
#include <stdint.h>

// Problem constants (from the reference)
#define B_ 2
#define N_ 2048      // 2^11
#define R_ 16384     // 2^14
#define NF_ 128
#define NH_ 3
#define PSTEP_ 3

// ---------------------------------------------------------------------------
// Kernel 1: extract one-hot indices.  Rm is (rows, N) with exactly one 1.0
// per row.  One wave (64 lanes) scans one row (8 KB) with float4 loads.
// ---------------------------------------------------------------------------
__global__ __launch_bounds__(256) void k_extract(const float* __restrict__ Rm,
                                                 int* __restrict__ idx, int rows) {
  const int wid = blockIdx.x * 4 + (threadIdx.x >> 6);
  if (wid >= rows) return;
  const int lane = threadIdx.x & 63;
  const float4* p = reinterpret_cast<const float4*>(Rm + (size_t)wid * N_);
  int found = 0;
  #pragma unroll
  for (int it = 0; it < N_ / 256; ++it) {   // 2048/4/64 = 8 float4 per lane
    const float4 v = p[it * 64 + lane];
    const int base = (it * 64 + lane) * 4;
    if (v.x != 0.f) found = base;
    if (v.y != 0.f) found = base + 1;
    if (v.z != 0.f) found = base + 2;
    if (v.w != 0.f) found = base + 3;
  }
  #pragma unroll
  for (int off = 32; off > 0; off >>= 1)
    found = max(found, __shfl_down(found, off, 64));
  if (lane == 0) idx[wid] = found;
}

// ---------------------------------------------------------------------------
// Kernel 2: particle_encode = relu(relu(x @ w0 + b0) @ w1 + b1)
// x = [s_delta_flat(9), a_cur(1)]  rows = B*N.  16 rows / block, 256 thr.
// ---------------------------------------------------------------------------
__global__ __launch_bounds__(256) void k_particle(
    const float* __restrict__ a_cur, const float* __restrict__ s_delta,
    const float* __restrict__ w0, const float* __restrict__ b0,
    const float* __restrict__ w1, const float* __restrict__ b1,
    float* __restrict__ pe) {
  __shared__ alignas(16) float w0s[10][NF_];
  __shared__ alignas(16) float wbuf[64][NF_];
  __shared__ float b0s[NF_], b1s[NF_];
  __shared__ float xs[16][10];
  __shared__ alignas(16) float hst[NF_][20];   // transposed hidden, padded
  const int t = threadIdx.x, f = t & 127, g = t >> 7;
  const int r0 = blockIdx.x * 16;
  for (int i = t; i < 10 * NF_; i += 256) w0s[i >> 7][i & 127] = w0[i];
  if (t < NF_) { b0s[t] = b0[t]; b1s[t] = b1[t]; }
  for (int i = t; i < 16 * 10; i += 256) {
    const int r = i / 10, k = i % 10;
    const int gr = r0 + r, b = gr >> 11, n = gr & (N_ - 1);
    xs[r][k] = (k < 9)
        ? s_delta[(((size_t)b * NH_ + (k / 3)) * N_ + n) * 3 + (k % 3)]
        : a_cur[gr];
  }
  __syncthreads();
  // layer 1 -> hst[f][r] (transposed)
  for (int r = g * 8; r < g * 8 + 8; ++r) {
    float a1 = b0s[f];
    #pragma unroll
    for (int k = 0; k < 10; ++k) a1 = fmaf(xs[r][k], w0s[k][f], a1);
    hst[f][r] = fmaxf(a1, 0.f);
  }
  // layer 2
  float acc[8];
  #pragma unroll
  for (int i = 0; i < 8; ++i) acc[i] = b1s[f];
  for (int h = 0; h < 2; ++h) {
    __syncthreads();            // hst stores visible / prior wbuf reads done
    for (int i = t; i < 64 * NF_; i += 256) wbuf[i >> 7][i & 127] = w1[h * 64 * NF_ + i];
    __syncthreads();
    for (int k = 0; k < 64; ++k) {
      const float w = wbuf[k][f];
      #pragma unroll
      for (int i = 0; i < 2; ++i) {
        const float4 x4 = *reinterpret_cast<const float4*>(&hst[h * 64 + k][g * 8 + i * 4]);
        acc[i*4+0] = fmaf(x4.x, w, acc[i*4+0]);
        acc[i*4+1] = fmaf(x4.y, w, acc[i*4+1]);
        acc[i*4+2] = fmaf(x4.z, w, acc[i*4+2]);
        acc[i*4+3] = fmaf(x4.w, w, acc[i*4+3]);
      }
    }
  }
  #pragma unroll
  for (int i = 0; i < 8; ++i)
    pe[(size_t)(r0 + g * 8 + i) * NF_ + f] = fmaxf(acc[i], 0.f);
}

// ---------------------------------------------------------------------------
// Kernel 3: relation_encode: 6 -> 128 -> 128 -> 128, relu each.
// 32 edges / block, 256 thr.  Edge features gathered via recv/send idx.
// ---------------------------------------------------------------------------
__global__ __launch_bounds__(256) void k_relation(
    const float* __restrict__ a_cur, const float* __restrict__ s_cur,
    const float* __restrict__ ea,
    const int* __restrict__ recv, const int* __restrict__ send,
    const float* __restrict__ w0, const float* __restrict__ b0,
    const float* __restrict__ w1, const float* __restrict__ b1,
    const float* __restrict__ w2, const float* __restrict__ b2,
    float* __restrict__ rel) {
  __shared__ alignas(16) float wbuf[64][NF_];
  __shared__ alignas(16) float w0s[6][NF_];
  __shared__ float bs0[NF_], bs1[NF_], bs2[NF_];
  __shared__ alignas(16) float xt[6][36];
  __shared__ alignas(16) float ht[NF_][36];
  __shared__ alignas(16) float ht2[NF_][36];
  const int t = threadIdx.x, f = t & 127, g = t >> 7;
  const int e0 = blockIdx.x * 32;
  for (int i = t; i < 6 * NF_; i += 256) w0s[i >> 7][i & 127] = w0[i];
  if (t < NF_) { bs0[t] = b0[t]; bs1[t] = b1[t]; bs2[t] = b2[t]; }
  if (t < 32) {
    const int ge = e0 + t;
    const int b = ge >> 14;
    const int rc = recv[ge], sd = send[ge];
    xt[0][t] = a_cur[(b << 11) + rc];
    xt[1][t] = a_cur[(b << 11) + sd];
    #pragma unroll
    for (int d = 0; d < 3; ++d)
      xt[2 + d][t] = s_cur[(size_t)((b << 11) + rc) * 3 + d]
                   - s_cur[(size_t)((b << 11) + sd) * 3 + d];
    xt[5][t] = ea[ge];
  }
  __syncthreads();
  // layer 1 (K=6)
  float acc[16];
  #pragma unroll
  for (int i = 0; i < 16; ++i) acc[i] = bs0[f];
  #pragma unroll
  for (int k = 0; k < 6; ++k) {
    const float w = w0s[k][f];
    #pragma unroll
    for (int i = 0; i < 4; ++i) {
      const float4 x4 = *reinterpret_cast<const float4*>(&xt[k][g * 16 + i * 4]);
      acc[i*4+0] = fmaf(x4.x, w, acc[i*4+0]);
      acc[i*4+1] = fmaf(x4.y, w, acc[i*4+1]);
      acc[i*4+2] = fmaf(x4.z, w, acc[i*4+2]);
      acc[i*4+3] = fmaf(x4.w, w, acc[i*4+3]);
    }
  }
  #pragma unroll
  for (int i = 0; i < 16; ++i) ht[f][g * 16 + i] = fmaxf(acc[i], 0.f);
  // layer 2 (K=128, weights staged in 2 halves)
  #pragma unroll
  for (int i = 0; i < 16; ++i) acc[i] = bs1[f];
  for (int h = 0; h < 2; ++h) {
    __syncthreads();
    for (int i = t; i < 64 * NF_; i += 256) wbuf[i >> 7][i & 127] = w1[h * 64 * NF_ + i];
    __syncthreads();
    for (int k = 0; k < 64; ++k) {
      const float w = wbuf[k][f];
      #pragma unroll
      for (int i = 0; i < 4; ++i) {
        const float4 x4 = *reinterpret_cast<const float4*>(&ht[h * 64 + k][g * 16 + i * 4]);
        acc[i*4+0] = fmaf(x4.x, w, acc[i*4+0]);
        acc[i*4+1] = fmaf(x4.y, w, acc[i*4+1]);
        acc[i*4+2] = fmaf(x4.z, w, acc[i*4+2]);
        acc[i*4+3] = fmaf(x4.w, w, acc[i*4+3]);
      }
    }
  }
  #pragma unroll
  for (int i = 0; i < 16; ++i) ht2[f][g * 16 + i] = fmaxf(acc[i], 0.f);
  // layer 3
  #pragma unroll
  for (int i = 0; i < 16; ++i) acc[i] = bs2[f];
  for (int h = 0; h < 2; ++h) {
    __syncthreads();             // ht2 stores visible / prior wbuf reads done
    for (int i = t; i < 64 * NF_; i += 256) wbuf[i >> 7][i & 127] = w2[h * 64 * NF_ + i];
    __syncthreads();
    for (int k = 0; k < 64; ++k) {
      const float w = wbuf[k][f];
      #pragma unroll
      for (int i = 0; i < 4; ++i) {
        const float4 x4 = *reinterpret_cast<const float4*>(&ht2[h * 64 + k][g * 16 + i * 4]);
        acc[i*4+0] = fmaf(x4.x, w, acc[i*4+0]);
        acc[i*4+1] = fmaf(x4.y, w, acc[i*4+1]);
        acc[i*4+2] = fmaf(x4.z, w, acc[i*4+2]);
        acc[i*4+3] = fmaf(x4.w, w, acc[i*4+3]);
      }
    }
  }
  #pragma unroll
  for (int i = 0; i < 16; ++i)
    rel[(size_t)(e0 + g * 16 + i) * NF_ + f] = fmaxf(acc[i], 0.f);
}

// ---------------------------------------------------------------------------
// Kernel: zero agg
// ---------------------------------------------------------------------------
__global__ __launch_bounds__(256) void k_zero(float4* __restrict__ p, int n4) {
  const int i = blockIdx.x * 256 + threadIdx.x;
  if (i < n4) p[i] = make_float4(0.f, 0.f, 0.f, 0.f);
}

// ---------------------------------------------------------------------------
// Kernel 5: e_rel = relu([rel, eff[recv], eff[send]] @ rp_w + rp_b)  (K=384)
// fused with atomic scatter-add into agg[recv].  64 edges / block.
// ---------------------------------------------------------------------------
__global__ __launch_bounds__(256) void k_erel(
    const float* __restrict__ rel, const float* __restrict__ eff_src,
    const int* __restrict__ recv, const int* __restrict__ send,
    const float* __restrict__ rp_w, const float* __restrict__ rp_b,
    float* __restrict__ agg) {
  __shared__ alignas(16) float wbuf[64][NF_];
  __shared__ alignas(16) float xt[NF_][68];
  __shared__ int idxs[2][64];
  const int t = threadIdx.x, f = t & 127, g = t >> 7;
  const int e0 = blockIdx.x * 64;
  if (t < 64) { idxs[0][t] = recv[e0 + t]; idxs[1][t] = send[e0 + t]; }
  float acc[32];
  {
    const float bias = rp_b[f];
    #pragma unroll
    for (int i = 0; i < 32; ++i) acc[i] = bias;
  }
  for (int c = 0; c < 3; ++c) {          // K-chunks: rel, eff[recv], eff[send]
    __syncthreads();                     // prior xt/wbuf reads done (& idxs visible)
    {
      const int e = t >> 2, k0 = (t & 3) * 32;
      const int ge = e0 + e;
      const float* src;
      if (c == 0) {
        src = rel + (size_t)ge * NF_;
      } else {
        const int b = ge >> 14;
        const int node = idxs[c - 1][e];
        src = eff_src + ((size_t)((b << 11) + node)) * NF_;
      }
      #pragma unroll
      for (int j = 0; j < 8; ++j) {
        const float4 v = *reinterpret_cast<const float4*>(src + k0 + j * 4);
        xt[k0 + j*4 + 0][e] = v.x;
        xt[k0 + j*4 + 1][e] = v.y;
        xt[k0 + j*4 + 2][e] = v.z;
        xt[k0 + j*4 + 3][e] = v.w;
      }
    }
    #pragma unroll 1
    for (int h = 0; h < 2; ++h) {
      __syncthreads();
      for (int i = t; i < 64 * NF_; i += 256)
        wbuf[i >> 7][i & 127] = rp_w[(size_t)(c * NF_ + h * 64) * NF_ + i];
      __syncthreads();
      for (int k = 0; k < 64; ++k) {
        const float w = wbuf[k][f];
        const int ka = h * 64 + k;
        #pragma unroll
        for (int i = 0; i < 8; ++i) {
          const float4 x4 = *reinterpret_cast<const float4*>(&xt[ka][g * 32 + i * 4]);
          acc[i*4+0] = fmaf(x4.x, w, acc[i*4+0]);
          acc[i*4+1] = fmaf(x4.y, w, acc[i*4+1]);
          acc[i*4+2] = fmaf(x4.z, w, acc[i*4+2]);
          acc[i*4+3] = fmaf(x4.w, w, acc[i*4+3]);
        }
      }
    }
  }
  const int b = e0 >> 14;
  #pragma unroll
  for (int i = 0; i < 32; ++i) {
    const int node = idxs[0][g * 32 + i];
    atomicAdd(&agg[((size_t)((b << 11) + node)) * NF_ + f], fmaxf(acc[i], 0.f));
  }
}

// ---------------------------------------------------------------------------
// Kernel 6: effect = relu([pe, agg] @ pp_w + pp_b + eff_src)   (K=256)
// 16 rows / block.
// ---------------------------------------------------------------------------
__global__ __launch_bounds__(256) void k_update(
    const float* __restrict__ pe, const float* __restrict__ agg,
    const float* __restrict__ eff_src,
    const float* __restrict__ pp_w, const float* __restrict__ pp_b,
    float* __restrict__ eff_out) {
  __shared__ alignas(16) float wbuf[64][NF_];
  __shared__ alignas(16) float xt[NF_][20];
  const int t = threadIdx.x, f = t & 127, g = t >> 7;
  const int r0 = blockIdx.x * 16;
  float acc[8];
  {
    const float bias = pp_b[f];
    #pragma unroll
    for (int i = 0; i < 8; ++i) acc[i] = bias;
  }
  for (int c = 0; c < 2; ++c) {          // K-chunks: pe, agg
    __syncthreads();
    {
      const int e = t >> 4, k0 = (t & 15) * 8;
      const float* src = (c ? agg : pe) + (size_t)(r0 + e) * NF_ + k0;
      #pragma unroll
      for (int j = 0; j < 2; ++j) {
        const float4 v = *reinterpret_cast<const float4*>(src + j * 4);
        xt[k0 + j*4 + 0][e] = v.x;
        xt[k0 + j*4 + 1][e] = v.y;
        xt[k0 + j*4 + 2][e] = v.z;
        xt[k0 + j*4 + 3][e] = v.w;
      }
    }
    #pragma unroll 1
    for (int h = 0; h < 2; ++h) {
      __syncthreads();
      for (int i = t; i < 64 * NF_; i += 256)
        wbuf[i >> 7][i & 127] = pp_w[(size_t)(c * NF_ + h * 64) * NF_ + i];
      __syncthreads();
      for (int k = 0; k < 64; ++k) {
        const float w = wbuf[k][f];
        const int ka = h * 64 + k;
        #pragma unroll
        for (int i = 0; i < 2; ++i) {
          const float4 x4 = *reinterpret_cast<const float4*>(&xt[ka][g * 8 + i * 4]);
          acc[i*4+0] = fmaf(x4.x, w, acc[i*4+0]);
          acc[i*4+1] = fmaf(x4.y, w, acc[i*4+1]);
          acc[i*4+2] = fmaf(x4.z, w, acc[i*4+2]);
          acc[i*4+3] = fmaf(x4.w, w, acc[i*4+3]);
        }
      }
    }
  }
  #pragma unroll
  for (int i = 0; i < 8; ++i) {
    const int r = r0 + g * 8 + i;
    eff_out[(size_t)r * NF_ + f] = fmaxf(acc[i] + eff_src[(size_t)r * NF_ + f], 0.f);
  }
}

// ---------------------------------------------------------------------------
// Kernel 7: pred = relu(eff @ pr_w0 + pr_b0) @ pr_w1 + pr_b1 + s_cur
// 16 rows / block.
// ---------------------------------------------------------------------------
__global__ __launch_bounds__(256) void k_predict(
    const float* __restrict__ eff, const float* __restrict__ s_cur,
    const float* __restrict__ w0, const float* __restrict__ b0,
    const float* __restrict__ w1, const float* __restrict__ b1,
    float* __restrict__ out) {
  __shared__ alignas(16) float wbuf[64][NF_];
  __shared__ alignas(16) float xt[NF_][20];
  __shared__ alignas(16) float ht[NF_][20];
  __shared__ float w1s[NF_][4];
  const int t = threadIdx.x, f = t & 127, g = t >> 7;
  const int r0 = blockIdx.x * 16;
  for (int i = t; i < NF_ * 3; i += 256) w1s[i / 3][i % 3] = w1[i];
  {
    const int e = t >> 4, k0 = (t & 15) * 8;
    const float* src = eff + (size_t)(r0 + e) * NF_ + k0;
    #pragma unroll
    for (int j = 0; j < 2; ++j) {
      const float4 v = *reinterpret_cast<const float4*>(src + j * 4);
      xt[k0 + j*4 + 0][e] = v.x;
      xt[k0 + j*4 + 1][e] = v.y;
      xt[k0 + j*4 + 2][e] = v.z;
      xt[k0 + j*4 + 3][e] = v.w;
    }
  }
  float acc[8];
  {
    const float bias = b0[f];
    #pragma unroll
    for (int i = 0; i < 8; ++i) acc[i] = bias;
  }
  for (int h = 0; h < 2; ++h) {
    __syncthreads();
    for (int i = t; i < 64 * NF_; i += 256) wbuf[i >> 7][i & 127] = w0[h * 64 * NF_ + i];
    __syncthreads();
    for (int k = 0; k < 64; ++k) {
      const float w = wbuf[k][f];
      const int ka = h * 64 + k;
      #pragma unroll
      for (int i = 0; i < 2; ++i) {
        const float4 x4 = *reinterpret_cast<const float4*>(&xt[ka][g * 8 + i * 4]);
        acc[i*4+0] = fmaf(x4.x, w, acc[i*4+0]);
        acc[i*4+1] = fmaf(x4.y, w, acc[i*4+1]);
        acc[i*4+2] = fmaf(x4.z, w, acc[i*4+2]);
        acc[i*4+3] = fmaf(x4.w, w, acc[i*4+3]);
      }
    }
  }
  #pragma unroll
  for (int i = 0; i < 8; ++i) ht[f][g * 8 + i] = fmaxf(acc[i], 0.f);
  __syncthreads();
  if (t < 48) {
    const int r = t / 3, d = t % 3;
    float a2 = b1[d];
    for (int k = 0; k < NF_; ++k) a2 = fmaf(ht[k][r], w1s[k][d], a2);
    const int gr = r0 + r;
    out[(size_t)gr * 3 + d] = a2 + s_cur[(size_t)gr * 3 + d];
  }
}

// ---------------------------------------------------------------------------
extern "C" void kernel_launch(void* const* d_in, const int* in_sizes, int n_in,
                              void* d_out, int out_size, void* d_ws, size_t ws_size,
                              hipStream_t stream) {
  (void)in_sizes; (void)n_in; (void)out_size; (void)ws_size;
  const float* a_cur   = (const float*)d_in[0];
  const float* s_cur   = (const float*)d_in[1];
  const float* s_delta = (const float*)d_in[2];
  const float* Rr      = (const float*)d_in[3];
  const float* Rs      = (const float*)d_in[4];
  const float* ea      = (const float*)d_in[5];
  const float* pe_w0 = (const float*)d_in[6];
  const float* pe_b0 = (const float*)d_in[7];
  const float* pe_w1 = (const float*)d_in[8];
  const float* pe_b1 = (const float*)d_in[9];
  const float* re_w0 = (const float*)d_in[10];
  const float* re_b0 = (const float*)d_in[11];
  const float* re_w1 = (const float*)d_in[12];
  const float* re_b1 = (const float*)d_in[13];
  const float* re_w2 = (const float*)d_in[14];
  const float* re_b2 = (const float*)d_in[15];
  const float* rp_w  = (const float*)d_in[16];
  const float* rp_b  = (const float*)d_in[17];
  const float* pp_w  = (const float*)d_in[18];
  const float* pp_b  = (const float*)d_in[19];
  const float* pr_w0 = (const float*)d_in[20];
  const float* pr_b0 = (const float*)d_in[21];
  const float* pr_w1 = (const float*)d_in[22];
  const float* pr_b1 = (const float*)d_in[23];
  float* out = (float*)d_out;

  uint8_t* wp = (uint8_t*)d_ws;
  auto alloc = [&](size_t bytes) {
    void* p = (void*)wp;
    wp += (bytes + 255) & ~(size_t)255;
    return p;
  };
  int*   recv = (int*)alloc((size_t)B_ * R_ * sizeof(int));
  int*   send = (int*)alloc((size_t)B_ * R_ * sizeof(int));
  float* pe   = (float*)alloc((size_t)B_ * N_ * NF_ * sizeof(float));
  float* eff  = (float*)alloc((size_t)B_ * N_ * NF_ * sizeof(float));
  float* agg  = (float*)alloc((size_t)B_ * N_ * NF_ * sizeof(float));
  float* rel  = (float*)alloc((size_t)B_ * R_ * NF_ * sizeof(float));

  const int rows_e = B_ * R_;                       // 32768 one-hot rows
  k_extract<<<rows_e / 4, 256, 0, stream>>>(Rr, recv, rows_e);
  k_extract<<<rows_e / 4, 256, 0, stream>>>(Rs, send, rows_e);

  k_particle<<<B_ * N_ / 16, 256, 0, stream>>>(a_cur, s_delta, pe_w0, pe_b0,
                                               pe_w1, pe_b1, pe);
  k_relation<<<B_ * R_ / 32, 256, 0, stream>>>(a_cur, s_cur, ea, recv, send,
                                               re_w0, re_b0, re_w1, re_b1,
                                               re_w2, re_b2, rel);

  const int agg_n4 = B_ * N_ * NF_ / 4;
  const float* esrc = pe;                           // effect starts as particle_encode
  for (int step = 0; step < PSTEP_; ++step) {
    k_zero<<<(agg_n4 + 255) / 256, 256, 0, stream>>>((float4*)agg, agg_n4);
    k_erel<<<B_ * R_ / 64, 256, 0, stream>>>(rel, esrc, recv, send, rp_w, rp_b, agg);
    k_update<<<B_ * N_ / 16, 256, 0, stream>>>(pe, agg, esrc, pp_w, pp_b, eff);
    esrc = eff;
  }

  k_predict<<<B_ * N_ / 16, 256, 0, stream>>>(eff, s_cur, pr_w0, pr_b0,
                                              pr_w1, pr_b1, out);
}

// Round 2
// 753.829 us; speedup vs baseline: 1.1971x; 1.1971x over previous
//
#include <hip/hip_runtime.h>
#include <hip/hip_bf16.h>
#include <stdint.h>

#define B_ 2
#define N_ 2048      // 2^11
#define R_ 16384     // 2^14
#define NF_ 128
#define NH_ 3
#define PSTEP_ 3
#define EDGES (B_ * R_)    // 32768
#define NODES (B_ * N_)    // 4096
#define MAXDEG 64

typedef _Float16 f16;
typedef _Float16 f16x4 __attribute__((ext_vector_type(4)));
typedef float f32x4 __attribute__((ext_vector_type(4)));

// ---------------------------------------------------------------------------
// global -> LDS async 16B/lane staging.  Dest is wave-uniform base + lane*16.
// ---------------------------------------------------------------------------
__device__ __forceinline__ void gl16(const f16* g, f16* l, int lane) {
#if defined(__has_builtin) && __has_builtin(__builtin_amdgcn_global_load_lds)
  typedef const __attribute__((address_space(1))) uint32_t* gas_t;
  typedef __attribute__((address_space(3))) uint32_t* las_t;
  __builtin_amdgcn_global_load_lds((gas_t)(const void*)g, (las_t)(void*)l, 16, 0, 0);
#else
  *(float4*)((char*)l + lane * 16) = *(const float4*)g;
#endif
}

// ---------------------------------------------------------------------------
// Kernel 1: extract one-hot indices for Rr and Rs.  One wave scans one row,
// early-exit per 1KB chunk (expected ~56% of the 536 MB stream).
// ---------------------------------------------------------------------------
__global__ __launch_bounds__(256) void k_extract(const float* __restrict__ Rr,
                                                 const float* __restrict__ Rs,
                                                 int* __restrict__ recv,
                                                 int* __restrict__ send) {
  const int wid = blockIdx.x * 4 + (threadIdx.x >> 6);   // 0..2*EDGES-1
  const int lane = threadIdx.x & 63;
  const bool isR = wid < EDGES;
  const int row = isR ? wid : wid - EDGES;
  const float4* p = reinterpret_cast<const float4*>((isR ? Rr : Rs) + (size_t)row * N_);
  int found = 0;
  #pragma unroll 1
  for (int it = 0; it < N_ / 256; ++it) {
    const float4 v = p[it * 64 + lane];
    const int base = (it * 64 + lane) * 4;
    bool hit = false;
    if (v.x != 0.f) { found = base;     hit = true; }
    if (v.y != 0.f) { found = base + 1; hit = true; }
    if (v.z != 0.f) { found = base + 2; hit = true; }
    if (v.w != 0.f) { found = base + 3; hit = true; }
    if (__any(hit)) break;
  }
  #pragma unroll
  for (int off = 32; off > 0; off >>= 1)
    found = max(found, __shfl_down(found, off, 64));
  if (lane == 0) (isR ? recv : send)[row] = found;
}

// ---------------------------------------------------------------------------
// Kernel 2: convert + transpose weights to f16 hi/lo (W^T layout) and zero
// the CSR counts.  rp_w: [384][128] -> rpT[n][k] (stride 384).
// re_w1/re_w2: [128][128] -> T (stride 128).
// ---------------------------------------------------------------------------
__global__ __launch_bounds__(256) void k_convw(
    const float* __restrict__ rp_w, const float* __restrict__ re_w1,
    const float* __restrict__ re_w2,
    f16* __restrict__ rpT_h, f16* __restrict__ rpT_l,
    f16* __restrict__ re1T_h, f16* __restrict__ re1T_l,
    f16* __restrict__ re2T_h, f16* __restrict__ re2T_l,
    int* __restrict__ counts) {
  const int i = blockIdx.x * 256 + threadIdx.x;
  const int S1 = 384 * 128, S2 = S1 + 128 * 128, S3 = S2 + 128 * 128;
  if (i < S1) {
    const int k = i >> 7, n = i & 127;
    const float v = rp_w[i];
    const f16 h = (f16)v;
    rpT_h[n * 384 + k] = h; rpT_l[n * 384 + k] = (f16)(v - (float)h);
  } else if (i < S2) {
    const int j = i - S1, k = j >> 7, n = j & 127;
    const float v = re_w1[j];
    const f16 h = (f16)v;
    re1T_h[n * 128 + k] = h; re1T_l[n * 128 + k] = (f16)(v - (float)h);
  } else if (i < S3) {
    const int j = i - S2, k = j >> 7, n = j & 127;
    const float v = re_w2[j];
    const f16 h = (f16)v;
    re2T_h[n * 128 + k] = h; re2T_l[n * 128 + k] = (f16)(v - (float)h);
  } else if (i < S3 + NODES) {
    counts[i - S3] = 0;
  }
}

// ---------------------------------------------------------------------------
// Kernel 3: CSR bucket fill: bucket[gnode][pos] = edge id.
// ---------------------------------------------------------------------------
__global__ __launch_bounds__(256) void k_bucket(const int* __restrict__ recv,
                                                int* __restrict__ counts,
                                                int* __restrict__ bucket) {
  const int e = blockIdx.x * 256 + threadIdx.x;
  if (e >= EDGES) return;
  const int gnode = (e >> 14) * N_ + recv[e];
  const int pos = atomicAdd(&counts[gnode], 1);
  if (pos < MAXDEG) bucket[gnode * MAXDEG + pos] = e;
}

// ---------------------------------------------------------------------------
// Kernel 4: particle_encode (vector fp32), writes f32 + f16 hi/lo.
// ---------------------------------------------------------------------------
__global__ __launch_bounds__(256) void k_particle(
    const float* __restrict__ a_cur, const float* __restrict__ s_delta,
    const float* __restrict__ w0, const float* __restrict__ b0,
    const float* __restrict__ w1, const float* __restrict__ b1,
    float* __restrict__ pe, f16* __restrict__ pe_h, f16* __restrict__ pe_l) {
  __shared__ alignas(16) float w0s[10][NF_];
  __shared__ alignas(16) float wbuf[64][NF_];
  __shared__ float b0s[NF_], b1s[NF_];
  __shared__ float xs[16][10];
  __shared__ alignas(16) float hst[NF_][20];
  const int t = threadIdx.x, f = t & 127, g = t >> 7;
  const int r0 = blockIdx.x * 16;
  for (int i = t; i < 10 * NF_; i += 256) w0s[i >> 7][i & 127] = w0[i];
  if (t < NF_) { b0s[t] = b0[t]; b1s[t] = b1[t]; }
  for (int i = t; i < 16 * 10; i += 256) {
    const int r = i / 10, k = i % 10;
    const int gr = r0 + r, b = gr >> 11, n = gr & (N_ - 1);
    xs[r][k] = (k < 9)
        ? s_delta[(((size_t)b * NH_ + (k / 3)) * N_ + n) * 3 + (k % 3)]
        : a_cur[gr];
  }
  __syncthreads();
  for (int r = g * 8; r < g * 8 + 8; ++r) {
    float a1 = b0s[f];
    #pragma unroll
    for (int k = 0; k < 10; ++k) a1 = fmaf(xs[r][k], w0s[k][f], a1);
    hst[f][r] = fmaxf(a1, 0.f);
  }
  float acc[8];
  #pragma unroll
  for (int i = 0; i < 8; ++i) acc[i] = b1s[f];
  for (int h = 0; h < 2; ++h) {
    __syncthreads();
    for (int i = t; i < 64 * NF_; i += 256) wbuf[i >> 7][i & 127] = w1[h * 64 * NF_ + i];
    __syncthreads();
    for (int k = 0; k < 64; ++k) {
      const float w = wbuf[k][f];
      #pragma unroll
      for (int i = 0; i < 2; ++i) {
        const float4 x4 = *reinterpret_cast<const float4*>(&hst[h * 64 + k][g * 8 + i * 4]);
        acc[i*4+0] = fmaf(x4.x, w, acc[i*4+0]);
        acc[i*4+1] = fmaf(x4.y, w, acc[i*4+1]);
        acc[i*4+2] = fmaf(x4.z, w, acc[i*4+2]);
        acc[i*4+3] = fmaf(x4.w, w, acc[i*4+3]);
      }
    }
  }
  #pragma unroll
  for (int i = 0; i < 8; ++i) {
    const size_t idx = (size_t)(r0 + g * 8 + i) * NF_ + f;
    const float v = fmaxf(acc[i], 0.f);
    pe[idx] = v;
    const f16 h = (f16)v;
    pe_h[idx] = h; pe_l[idx] = (f16)(v - (float)h);
  }
}

// ---------------------------------------------------------------------------
// Kernel 5: relation layer 1 (K=6, vector) -> h1 f16 hi/lo.
// ---------------------------------------------------------------------------
__global__ __launch_bounds__(256) void k_rel1(
    const float* __restrict__ a_cur, const float* __restrict__ s_cur,
    const float* __restrict__ ea,
    const int* __restrict__ recv, const int* __restrict__ send,
    const float* __restrict__ w0, const float* __restrict__ b0,
    f16* __restrict__ h1_h, f16* __restrict__ h1_l) {
  __shared__ alignas(16) float w0s[6][NF_];
  __shared__ float bs0[NF_];
  __shared__ alignas(16) float xt[6][36];
  const int t = threadIdx.x, f = t & 127, g = t >> 7;
  const int e0 = blockIdx.x * 32;
  for (int i = t; i < 6 * NF_; i += 256) w0s[i >> 7][i & 127] = w0[i];
  if (t < NF_) bs0[t] = b0[t];
  if (t < 32) {
    const int ge = e0 + t;
    const int b = ge >> 14;
    const int rc = recv[ge], sd = send[ge];
    xt[0][t] = a_cur[(b << 11) + rc];
    xt[1][t] = a_cur[(b << 11) + sd];
    #pragma unroll
    for (int d = 0; d < 3; ++d)
      xt[2 + d][t] = s_cur[(size_t)((b << 11) + rc) * 3 + d]
                   - s_cur[(size_t)((b << 11) + sd) * 3 + d];
    xt[5][t] = ea[ge];
  }
  __syncthreads();
  float acc[16];
  #pragma unroll
  for (int i = 0; i < 16; ++i) acc[i] = bs0[f];
  #pragma unroll
  for (int k = 0; k < 6; ++k) {
    const float w = w0s[k][f];
    #pragma unroll
    for (int i = 0; i < 4; ++i) {
      const float4 x4 = *reinterpret_cast<const float4*>(&xt[k][g * 16 + i * 4]);
      acc[i*4+0] = fmaf(x4.x, w, acc[i*4+0]);
      acc[i*4+1] = fmaf(x4.y, w, acc[i*4+1]);
      acc[i*4+2] = fmaf(x4.z, w, acc[i*4+2]);
      acc[i*4+3] = fmaf(x4.w, w, acc[i*4+3]);
    }
  }
  #pragma unroll
  for (int i = 0; i < 16; ++i) {
    const size_t idx = (size_t)(e0 + g * 16 + i) * NF_ + f;
    const float v = fmaxf(acc[i], 0.f);
    const f16 h = (f16)v;
    h1_h[idx] = h; h1_l[idx] = (f16)(v - (float)h);
  }
}

// ---------------------------------------------------------------------------
// Kernel 6: MFMA GEMM  C[M][128] = relu(A[M][128] @ W + bias), split-f16.
// A given as hi/lo [M][128]; W given as W^T hi/lo [128 n][128 k].
// Block: 128 rows, 4 waves (wave = 128x32 tile).  LDS 128 KB, XOR-swizzled
// via pre-swizzled global source (T2/m173 pattern).
// ---------------------------------------------------------------------------
__global__ __launch_bounds__(256, 1) void k_gemm128(
    const f16* __restrict__ Ah_g, const f16* __restrict__ Al_g,
    const f16* __restrict__ Bh_g, const f16* __restrict__ Bl_g,
    const float* __restrict__ bias,
    f16* __restrict__ Ch, f16* __restrict__ Cl) {
  __shared__ f16 Ah[128 * 128], Al[128 * 128], Bh[128 * 128], Bl[128 * 128];
  const int t = threadIdx.x, lane = t & 63, w = t >> 6;
  const int l16 = lane & 15, l4 = lane >> 4;
  const size_t brow = (size_t)blockIdx.x * 128;
  // stage (each wave: 32 rows of A and of B, both splits)
  #pragma unroll
  for (int rb = 0; rb < 32; rb += 4) {
    const int r0 = w * 32 + rb;
    const int row = r0 + l4;
    const int sc = (l16 ^ (row & 7)) * 8;   // f16 offset of swizzled 16B slot
    gl16(Ah_g + (brow + row) * 128 + sc, &Ah[r0 * 128], lane);
    gl16(Al_g + (brow + row) * 128 + sc, &Al[r0 * 128], lane);
    gl16(Bh_g + (size_t)row * 128 + sc, &Bh[r0 * 128], lane);
    gl16(Bl_g + (size_t)row * 128 + sc, &Bl[r0 * 128], lane);
  }
  float bv[2];
  bv[0] = bias[w * 32 + l16];
  bv[1] = bias[w * 32 + 16 + l16];
  f32x4 acc[8][2];
  #pragma unroll
  for (int m = 0; m < 8; ++m)
    #pragma unroll
    for (int nf = 0; nf < 2; ++nf)
      acc[m][nf] = (f32x4){bv[nf], bv[nf], bv[nf], bv[nf]};
  __syncthreads();
  #pragma unroll 1
  for (int kk = 0; kk < 8; ++kk) {         // K-steps of 16
    const int c16 = kk * 2 + (l4 >> 1);
    const int sub = (l4 & 1) * 4;
    f16x4 bh[2], bl[2];
    #pragma unroll
    for (int nf = 0; nf < 2; ++nf) {
      const int n = w * 32 + nf * 16 + l16;
      const int off = n * 128 + (c16 ^ (n & 7)) * 8 + sub;
      bh[nf] = *(const f16x4*)&Bh[off];
      bl[nf] = *(const f16x4*)&Bl[off];
    }
    #pragma unroll
    for (int m = 0; m < 8; ++m) {
      const int r = m * 16 + l16;
      const int off = r * 128 + (c16 ^ (r & 7)) * 8 + sub;
      const f16x4 ah = *(const f16x4*)&Ah[off];
      const f16x4 al = *(const f16x4*)&Al[off];
      #pragma unroll
      for (int nf = 0; nf < 2; ++nf) {
        acc[m][nf] = __builtin_amdgcn_mfma_f32_16x16x16f16(ah, bh[nf], acc[m][nf], 0, 0, 0);
        acc[m][nf] = __builtin_amdgcn_mfma_f32_16x16x16f16(ah, bl[nf], acc[m][nf], 0, 0, 0);
        acc[m][nf] = __builtin_amdgcn_mfma_f32_16x16x16f16(al, bh[nf], acc[m][nf], 0, 0, 0);
      }
    }
  }
  #pragma unroll
  for (int m = 0; m < 8; ++m)
    #pragma unroll
    for (int nf = 0; nf < 2; ++nf)
      #pragma unroll
      for (int i = 0; i < 4; ++i) {
        const float v = fmaxf(acc[m][nf][i], 0.f);
        const size_t row = brow + m * 16 + l4 * 4 + i;
        const int col = w * 32 + nf * 16 + l16;
        const f16 h = (f16)v;
        Ch[row * 128 + col] = h;
        Cl[row * 128 + col] = (f16)(v - (float)h);
      }
}

// ---------------------------------------------------------------------------
// Kernel 7: MFMA erel GEMM, K=384 in 3 chunks {rel, eff[recv], eff[send]},
// gathered A rows, fp32 relu output (for gather-aggregation).
// ---------------------------------------------------------------------------
__global__ __launch_bounds__(256, 1) void k_gemm_erel(
    const f16* __restrict__ rel_h, const f16* __restrict__ rel_l,
    const f16* __restrict__ eff_h, const f16* __restrict__ eff_l,
    const int* __restrict__ recv, const int* __restrict__ send,
    const f16* __restrict__ rpT_h, const f16* __restrict__ rpT_l,
    const float* __restrict__ bias, float* __restrict__ e_rel) {
  __shared__ f16 Ah[128 * 128], Al[128 * 128], Bh[128 * 128], Bl[128 * 128];
  const int t = threadIdx.x, lane = t & 63, w = t >> 6;
  const int l16 = lane & 15, l4 = lane >> 4;
  const size_t brow = (size_t)blockIdx.x * 128;
  float bv[2];
  bv[0] = bias[w * 32 + l16];
  bv[1] = bias[w * 32 + 16 + l16];
  f32x4 acc[8][2];
  #pragma unroll
  for (int m = 0; m < 8; ++m)
    #pragma unroll
    for (int nf = 0; nf < 2; ++nf)
      acc[m][nf] = (f32x4){bv[nf], bv[nf], bv[nf], bv[nf]};
  #pragma unroll 1
  for (int ch = 0; ch < 3; ++ch) {
    if (ch) __syncthreads();           // all reads of previous chunk done
    #pragma unroll
    for (int rb = 0; rb < 32; rb += 4) {
      const int r0 = w * 32 + rb;
      const int row = r0 + l4;
      const int sc = (l16 ^ (row & 7)) * 8;
      const int ge = (int)brow + row;
      const f16 *sh, *sl; size_t aoff;
      if (ch == 0) { sh = rel_h; sl = rel_l; aoff = (size_t)ge * 128; }
      else {
        const int node = (ch == 1) ? recv[ge] : send[ge];
        sh = eff_h; sl = eff_l;
        aoff = (size_t)((ge >> 14) * N_ + node) * 128;
      }
      gl16(sh + aoff + sc, &Ah[r0 * 128], lane);
      gl16(sl + aoff + sc, &Al[r0 * 128], lane);
      gl16(rpT_h + (size_t)row * 384 + ch * 128 + sc, &Bh[r0 * 128], lane);
      gl16(rpT_l + (size_t)row * 384 + ch * 128 + sc, &Bl[r0 * 128], lane);
    }
    __syncthreads();
    #pragma unroll 1
    for (int kk = 0; kk < 8; ++kk) {
      const int c16 = kk * 2 + (l4 >> 1);
      const int sub = (l4 & 1) * 4;
      f16x4 bh[2], bl[2];
      #pragma unroll
      for (int nf = 0; nf < 2; ++nf) {
        const int n = w * 32 + nf * 16 + l16;
        const int off = n * 128 + (c16 ^ (n & 7)) * 8 + sub;
        bh[nf] = *(const f16x4*)&Bh[off];
        bl[nf] = *(const f16x4*)&Bl[off];
      }
      #pragma unroll
      for (int m = 0; m < 8; ++m) {
        const int r = m * 16 + l16;
        const int off = r * 128 + (c16 ^ (r & 7)) * 8 + sub;
        const f16x4 ah = *(const f16x4*)&Ah[off];
        const f16x4 al = *(const f16x4*)&Al[off];
        #pragma unroll
        for (int nf = 0; nf < 2; ++nf) {
          acc[m][nf] = __builtin_amdgcn_mfma_f32_16x16x16f16(ah, bh[nf], acc[m][nf], 0, 0, 0);
          acc[m][nf] = __builtin_amdgcn_mfma_f32_16x16x16f16(ah, bl[nf], acc[m][nf], 0, 0, 0);
          acc[m][nf] = __builtin_amdgcn_mfma_f32_16x16x16f16(al, bh[nf], acc[m][nf], 0, 0, 0);
        }
      }
    }
  }
  #pragma unroll
  for (int m = 0; m < 8; ++m)
    #pragma unroll
    for (int nf = 0; nf < 2; ++nf)
      #pragma unroll
      for (int i = 0; i < 4; ++i) {
        const float v = fmaxf(acc[m][nf][i], 0.f);
        const size_t row = brow + m * 16 + l4 * 4 + i;
        const int col = w * 32 + nf * 16 + l16;
        e_rel[row * 128 + col] = v;
      }
}

// ---------------------------------------------------------------------------
// Kernel 8: gather aggregation  agg[gnode][f] = sum over bucket edges.
// ---------------------------------------------------------------------------
__global__ __launch_bounds__(256) void k_agg(
    const float* __restrict__ e_rel, const int* __restrict__ counts,
    const int* __restrict__ bucket, float* __restrict__ agg) {
  const int t = threadIdx.x, f = t & 127;
  const int gnode = blockIdx.x * 2 + (t >> 7);
  const int cnt = min(counts[gnode], MAXDEG);
  float s = 0.f;
  for (int i = 0; i < cnt; ++i) {
    const int e = bucket[gnode * MAXDEG + i];
    s += e_rel[(size_t)e * NF_ + f];
  }
  agg[(size_t)gnode * NF_ + f] = s;
}

// ---------------------------------------------------------------------------
// Kernel 9: effect = relu([pe, agg] @ pp_w + pp_b + eff_src)  (vector fp32),
// writes f32 + f16 hi/lo.
// ---------------------------------------------------------------------------
__global__ __launch_bounds__(256) void k_update(
    const float* __restrict__ pe, const float* __restrict__ agg,
    const float* __restrict__ eff_src,
    const float* __restrict__ pp_w, const float* __restrict__ pp_b,
    float* __restrict__ eff_out, f16* __restrict__ eh, f16* __restrict__ el) {
  __shared__ alignas(16) float wbuf[64][NF_];
  __shared__ alignas(16) float xt[NF_][20];
  const int t = threadIdx.x, f = t & 127, g = t >> 7;
  const int r0 = blockIdx.x * 16;
  float acc[8];
  {
    const float bias = pp_b[f];
    #pragma unroll
    for (int i = 0; i < 8; ++i) acc[i] = bias;
  }
  for (int c = 0; c < 2; ++c) {
    __syncthreads();
    {
      const int e = t >> 4, k0 = (t & 15) * 8;
      const float* src = (c ? agg : pe) + (size_t)(r0 + e) * NF_ + k0;
      #pragma unroll
      for (int j = 0; j < 2; ++j) {
        const float4 v = *reinterpret_cast<const float4*>(src + j * 4);
        xt[k0 + j*4 + 0][e] = v.x;
        xt[k0 + j*4 + 1][e] = v.y;
        xt[k0 + j*4 + 2][e] = v.z;
        xt[k0 + j*4 + 3][e] = v.w;
      }
    }
    #pragma unroll 1
    for (int h = 0; h < 2; ++h) {
      __syncthreads();
      for (int i = t; i < 64 * NF_; i += 256)
        wbuf[i >> 7][i & 127] = pp_w[(size_t)(c * NF_ + h * 64) * NF_ + i];
      __syncthreads();
      for (int k = 0; k < 64; ++k) {
        const float w = wbuf[k][f];
        const int ka = h * 64 + k;
        #pragma unroll
        for (int i = 0; i < 2; ++i) {
          const float4 x4 = *reinterpret_cast<const float4*>(&xt[ka][g * 8 + i * 4]);
          acc[i*4+0] = fmaf(x4.x, w, acc[i*4+0]);
          acc[i*4+1] = fmaf(x4.y, w, acc[i*4+1]);
          acc[i*4+2] = fmaf(x4.z, w, acc[i*4+2]);
          acc[i*4+3] = fmaf(x4.w, w, acc[i*4+3]);
        }
      }
    }
  }
  #pragma unroll
  for (int i = 0; i < 8; ++i) {
    const size_t idx = (size_t)(r0 + g * 8 + i) * NF_ + f;
    const float v = fmaxf(acc[i] + eff_src[idx], 0.f);
    eff_out[idx] = v;
    const f16 h = (f16)v;
    eh[idx] = h; el[idx] = (f16)(v - (float)h);
  }
}

// ---------------------------------------------------------------------------
// Kernel 10: pred = relu(eff @ pr_w0 + pr_b0) @ pr_w1 + pr_b1 + s_cur.
// ---------------------------------------------------------------------------
__global__ __launch_bounds__(256) void k_predict(
    const float* __restrict__ eff, const float* __restrict__ s_cur,
    const float* __restrict__ w0, const float* __restrict__ b0,
    const float* __restrict__ w1, const float* __restrict__ b1,
    float* __restrict__ out) {
  __shared__ alignas(16) float wbuf[64][NF_];
  __shared__ alignas(16) float xt[NF_][20];
  __shared__ alignas(16) float ht[NF_][20];
  __shared__ float w1s[NF_][4];
  const int t = threadIdx.x, f = t & 127, g = t >> 7;
  const int r0 = blockIdx.x * 16;
  for (int i = t; i < NF_ * 3; i += 256) w1s[i / 3][i % 3] = w1[i];
  {
    const int e = t >> 4, k0 = (t & 15) * 8;
    const float* src = eff + (size_t)(r0 + e) * NF_ + k0;
    #pragma unroll
    for (int j = 0; j < 2; ++j) {
      const float4 v = *reinterpret_cast<const float4*>(src + j * 4);
      xt[k0 + j*4 + 0][e] = v.x;
      xt[k0 + j*4 + 1][e] = v.y;
      xt[k0 + j*4 + 2][e] = v.z;
      xt[k0 + j*4 + 3][e] = v.w;
    }
  }
  float acc[8];
  {
    const float bias = b0[f];
    #pragma unroll
    for (int i = 0; i < 8; ++i) acc[i] = bias;
  }
  for (int h = 0; h < 2; ++h) {
    __syncthreads();
    for (int i = t; i < 64 * NF_; i += 256) wbuf[i >> 7][i & 127] = w0[h * 64 * NF_ + i];
    __syncthreads();
    for (int k = 0; k < 64; ++k) {
      const float w = wbuf[k][f];
      const int ka = h * 64 + k;
      #pragma unroll
      for (int i = 0; i < 2; ++i) {
        const float4 x4 = *reinterpret_cast<const float4*>(&xt[ka][g * 8 + i * 4]);
        acc[i*4+0] = fmaf(x4.x, w, acc[i*4+0]);
        acc[i*4+1] = fmaf(x4.y, w, acc[i*4+1]);
        acc[i*4+2] = fmaf(x4.z, w, acc[i*4+2]);
        acc[i*4+3] = fmaf(x4.w, w, acc[i*4+3]);
      }
    }
  }
  #pragma unroll
  for (int i = 0; i < 8; ++i) ht[f][g * 8 + i] = fmaxf(acc[i], 0.f);
  __syncthreads();
  if (t < 48) {
    const int r = t / 3, d = t % 3;
    float a2 = b1[d];
    for (int k = 0; k < NF_; ++k) a2 = fmaf(ht[k][r], w1s[k][d], a2);
    const int gr = r0 + r;
    out[(size_t)gr * 3 + d] = a2 + s_cur[(size_t)gr * 3 + d];
  }
}

// ---------------------------------------------------------------------------
extern "C" void kernel_launch(void* const* d_in, const int* in_sizes, int n_in,
                              void* d_out, int out_size, void* d_ws, size_t ws_size,
                              hipStream_t stream) {
  (void)in_sizes; (void)n_in; (void)out_size; (void)ws_size;
  const float* a_cur   = (const float*)d_in[0];
  const float* s_cur   = (const float*)d_in[1];
  const float* s_delta = (const float*)d_in[2];
  const float* Rr      = (const float*)d_in[3];
  const float* Rs      = (const float*)d_in[4];
  const float* ea      = (const float*)d_in[5];
  const float* pe_w0 = (const float*)d_in[6];
  const float* pe_b0 = (const float*)d_in[7];
  const float* pe_w1 = (const float*)d_in[8];
  const float* pe_b1 = (const float*)d_in[9];
  const float* re_w0 = (const float*)d_in[10];
  const float* re_b0 = (const float*)d_in[11];
  const float* re_w1 = (const float*)d_in[12];
  const float* re_b1 = (const float*)d_in[13];
  const float* re_w2 = (const float*)d_in[14];
  const float* re_b2 = (const float*)d_in[15];
  const float* rp_w  = (const float*)d_in[16];
  const float* rp_b  = (const float*)d_in[17];
  const float* pp_w  = (const float*)d_in[18];
  const float* pp_b  = (const float*)d_in[19];
  const float* pr_w0 = (const float*)d_in[20];
  const float* pr_b0 = (const float*)d_in[21];
  const float* pr_w1 = (const float*)d_in[22];
  const float* pr_b1 = (const float*)d_in[23];
  float* out = (float*)d_out;

  uint8_t* wp = (uint8_t*)d_ws;
  auto alloc = [&](size_t bytes) {
    void* p = (void*)wp;
    wp += (bytes + 255) & ~(size_t)255;
    return p;
  };
  int* recv   = (int*)alloc(EDGES * 4);
  int* send   = (int*)alloc(EDGES * 4);
  int* counts = (int*)alloc(NODES * 4);
  int* bucket = (int*)alloc((size_t)NODES * MAXDEG * 4);
  float* pe   = (float*)alloc((size_t)NODES * NF_ * 4);
  f16* pe_h   = (f16*)alloc((size_t)NODES * NF_ * 2);
  f16* pe_l   = (f16*)alloc((size_t)NODES * NF_ * 2);
  float* eff  = (float*)alloc((size_t)NODES * NF_ * 4);
  f16* eff_h  = (f16*)alloc((size_t)NODES * NF_ * 2);
  f16* eff_l  = (f16*)alloc((size_t)NODES * NF_ * 2);
  float* agg  = (float*)alloc((size_t)NODES * NF_ * 4);
  f16* h1_h   = (f16*)alloc((size_t)EDGES * NF_ * 2);
  f16* h1_l   = (f16*)alloc((size_t)EDGES * NF_ * 2);
  f16* h2_h   = (f16*)alloc((size_t)EDGES * NF_ * 2);
  f16* h2_l   = (f16*)alloc((size_t)EDGES * NF_ * 2);
  f16* rel_h  = (f16*)alloc((size_t)EDGES * NF_ * 2);
  f16* rel_l  = (f16*)alloc((size_t)EDGES * NF_ * 2);
  float* e_rel = (float*)alloc((size_t)EDGES * NF_ * 4);
  f16* rpT_h  = (f16*)alloc(128 * 384 * 2);
  f16* rpT_l  = (f16*)alloc(128 * 384 * 2);
  f16* re1T_h = (f16*)alloc(128 * 128 * 2);
  f16* re1T_l = (f16*)alloc(128 * 128 * 2);
  f16* re2T_h = (f16*)alloc(128 * 128 * 2);
  f16* re2T_l = (f16*)alloc(128 * 128 * 2);

  k_extract<<<(2 * EDGES) / 4, 256, 0, stream>>>(Rr, Rs, recv, send);
  k_convw<<<(384*128 + 2*128*128 + NODES + 255) / 256, 256, 0, stream>>>(
      rp_w, re_w1, re_w2, rpT_h, rpT_l, re1T_h, re1T_l, re2T_h, re2T_l, counts);
  k_bucket<<<EDGES / 256, 256, 0, stream>>>(recv, counts, bucket);
  k_particle<<<NODES / 16, 256, 0, stream>>>(a_cur, s_delta, pe_w0, pe_b0,
                                             pe_w1, pe_b1, pe, pe_h, pe_l);
  k_rel1<<<EDGES / 32, 256, 0, stream>>>(a_cur, s_cur, ea, recv, send,
                                         re_w0, re_b0, h1_h, h1_l);
  k_gemm128<<<EDGES / 128, 256, 0, stream>>>(h1_h, h1_l, re1T_h, re1T_l,
                                             re_b1, h2_h, h2_l);
  k_gemm128<<<EDGES / 128, 256, 0, stream>>>(h2_h, h2_l, re2T_h, re2T_l,
                                             re_b2, rel_h, rel_l);

  const float* esrc = pe;
  const f16* esrc_h = pe_h;
  const f16* esrc_l = pe_l;
  for (int step = 0; step < PSTEP_; ++step) {
    k_gemm_erel<<<EDGES / 128, 256, 0, stream>>>(rel_h, rel_l, esrc_h, esrc_l,
                                                 recv, send, rpT_h, rpT_l,
                                                 rp_b, e_rel);
    k_agg<<<NODES / 2, 256, 0, stream>>>(e_rel, counts, bucket, agg);
    k_update<<<NODES / 16, 256, 0, stream>>>(pe, agg, esrc, pp_w, pp_b,
                                             eff, eff_h, eff_l);
    esrc = eff; esrc_h = eff_h; esrc_l = eff_l;
  }

  k_predict<<<NODES / 16, 256, 0, stream>>>(eff, s_cur, pr_w0, pr_b0,
                                            pr_w1, pr_b1, out);
}

// Round 5
// 702.061 us; speedup vs baseline: 1.2854x; 1.0737x over previous
//
#include <hip/hip_runtime.h>
#include <hip/hip_bf16.h>
#include <stdint.h>

#define B_ 2
#define N_ 2048      // 2^11
#define R_ 16384     // 2^14
#define NF_ 128
#define NH_ 3
#define PSTEP_ 3
#define EDGES (B_ * R_)    // 32768
#define NODES (B_ * N_)    // 4096
#define PREP_EXB0 1024

typedef _Float16 f16;
typedef _Float16 f16x4 __attribute__((ext_vector_type(4)));
typedef float f32x4 __attribute__((ext_vector_type(4)));

struct GemmLds { f16 Ah[128 * 128], Al[128 * 128], Bh[128 * 128], Bl[128 * 128]; }; // 128 KB
struct VecLds {
  float wbuf[64][NF_];          // 32 KB
  float xt[NF_][20];            // 10 KB
  float ht[NF_][20];            // 10 KB
  float w0s[10][NF_];
  float b0s[NF_], b1s[NF_];
  float xs[16][10];
  float w1s[NF_][4];
};
union MainLds { GemmLds g; VecLds v; };

// ---------------------------------------------------------------------------
__device__ __forceinline__ void gl16(const f16* g, f16* l) {
  typedef const __attribute__((address_space(1))) uint32_t* gas_t;
  typedef __attribute__((address_space(3))) uint32_t* las_t;
  __builtin_amdgcn_global_load_lds((gas_t)(const void*)g, (las_t)(void*)l, 16, 0, 0);
}

// 128x128x128 split-f16 MFMA block GEMM step (A,B staged in LDS, swizzled).
__device__ __forceinline__ void mfma_block(const f16* Ah, const f16* Al,
                                           const f16* Bh, const f16* Bl,
                                           f32x4 (&acc)[8][2], int lane, int w) {
  const int l16 = lane & 15, l4 = lane >> 4;
  #pragma unroll 1
  for (int kk = 0; kk < 8; ++kk) {
    const int c16 = kk * 2 + (l4 >> 1);
    const int sub = (l4 & 1) * 4;
    f16x4 bh[2], bl[2];
    #pragma unroll
    for (int nf = 0; nf < 2; ++nf) {
      const int n = w * 32 + nf * 16 + l16;
      const int off = n * 128 + ((c16 ^ (n & 7)) * 8) + sub;
      bh[nf] = *(const f16x4*)&Bh[off];
      bl[nf] = *(const f16x4*)&Bl[off];
    }
    #pragma unroll
    for (int m = 0; m < 8; ++m) {
      const int r = m * 16 + l16;
      const int off = r * 128 + ((c16 ^ (r & 7)) * 8) + sub;
      const f16x4 ah = *(const f16x4*)&Ah[off];
      const f16x4 al = *(const f16x4*)&Al[off];
      #pragma unroll
      for (int nf = 0; nf < 2; ++nf) {
        acc[m][nf] = __builtin_amdgcn_mfma_f32_16x16x16f16(ah, bh[nf], acc[m][nf], 0, 0, 0);
        acc[m][nf] = __builtin_amdgcn_mfma_f32_16x16x16f16(ah, bl[nf], acc[m][nf], 0, 0, 0);
        acc[m][nf] = __builtin_amdgcn_mfma_f32_16x16x16f16(al, bh[nf], acc[m][nf], 0, 0, 0);
      }
    }
  }
}

// relu + split-f16 frag write back into swizzled LDS A-tile.
__device__ __forceinline__ void frags_to_lds(f32x4 (&acc)[8][2], f16* Ah, f16* Al,
                                             int lane, int w) {
  const int l16 = lane & 15, l4 = lane >> 4;
  #pragma unroll
  for (int m = 0; m < 8; ++m)
    #pragma unroll
    for (int nf = 0; nf < 2; ++nf)
      #pragma unroll
      for (int i = 0; i < 4; ++i) {
        const float v = fmaxf(acc[m][nf][i], 0.f);
        const int row = m * 16 + l4 * 4 + i;
        const int col = w * 32 + nf * 16 + l16;
        const int off = row * 128 + (((col >> 3) ^ (row & 7)) * 8) + (col & 7);
        const f16 h = (f16)v;
        Ah[off] = h; Al[off] = (f16)(v - (float)h);
      }
}

// ---------------------------------------------------------------------------
// Launch 1: extract one-hot indices + weight convert/transpose + zero agg.
// ---------------------------------------------------------------------------
__global__ __launch_bounds__(256) void k_prep(
    const float* __restrict__ Rr, const float* __restrict__ Rs,
    const float* __restrict__ rp_w, const float* __restrict__ re_w1,
    const float* __restrict__ re_w2,
    int* __restrict__ recv, int* __restrict__ send,
    f16* __restrict__ rpT_h, f16* __restrict__ rpT_l,
    f16* __restrict__ re1T_h, f16* __restrict__ re1T_l,
    f16* __restrict__ re2T_h, f16* __restrict__ re2T_l,
    float4* __restrict__ agg4) {
  const int bid = blockIdx.x, t = threadIdx.x;
  if (bid < 512) {                         // zero agg (4096*128 f32 = 131072 f4)
    agg4[bid * 256 + t] = make_float4(0.f, 0.f, 0.f, 0.f);
  } else if (bid >= 513 && bid < 833) {    // weight convert (81920 elements)
    const int i = (bid - 513) * 256 + t;
    const int S1 = 384 * 128, S2 = S1 + 128 * 128, S3 = S2 + 128 * 128;
    if (i < S1) {
      const int k = i >> 7, n = i & 127;
      const float v = rp_w[i];
      const f16 h = (f16)v;
      rpT_h[n * 384 + k] = h; rpT_l[n * 384 + k] = (f16)(v - (float)h);
    } else if (i < S2) {
      const int j = i - S1, k = j >> 7, n = j & 127;
      const float v = re_w1[j];
      const f16 h = (f16)v;
      re1T_h[n * 128 + k] = h; re1T_l[n * 128 + k] = (f16)(v - (float)h);
    } else if (i < S3) {
      const int j = i - S2, k = j >> 7, n = j & 127;
      const float v = re_w2[j];
      const f16 h = (f16)v;
      re2T_h[n * 128 + k] = h; re2T_l[n * 128 + k] = (f16)(v - (float)h);
    }
  } else if (bid >= PREP_EXB0) {           // extract: one wave per one-hot row
    const int wid = (bid - PREP_EXB0) * 4 + (t >> 6);
    const int lane = t & 63;
    const bool isR = wid < EDGES;
    const int row = isR ? wid : wid - EDGES;
    const float4* p = reinterpret_cast<const float4*>((isR ? Rr : Rs) + (size_t)row * N_);
    int found = 0;
    #pragma unroll 1
    for (int it = 0; it < N_ / 256; ++it) {
      const float4 v = p[it * 64 + lane];
      const int base = (it * 64 + lane) * 4;
      bool hit = false;
      if (v.x != 0.f) { found = base;     hit = true; }
      if (v.y != 0.f) { found = base + 1; hit = true; }
      if (v.z != 0.f) { found = base + 2; hit = true; }
      if (v.w != 0.f) { found = base + 3; hit = true; }
      if (__any(hit)) break;
    }
    #pragma unroll
    for (int off = 32; off > 0; off >>= 1)
      found = max(found, __shfl_down(found, off, 64));
    if (lane == 0) (isR ? recv : send)[row] = found;
  }
}

// ---------------------------------------------------------------------------
// Launch 2: particle_encode (16 nodes/block) + relation L1+L2+L3 fused
// (128 edges/block).  256 blocks, no cross-block dependencies.
// ---------------------------------------------------------------------------
__global__ __launch_bounds__(256, 1) void k_pre(
    const float* __restrict__ a_cur, const float* __restrict__ s_cur,
    const float* __restrict__ s_delta, const float* __restrict__ ea,
    const int* __restrict__ recv, const int* __restrict__ send,
    const float* __restrict__ pe_w0, const float* __restrict__ pe_b0,
    const float* __restrict__ pe_w1, const float* __restrict__ pe_b1,
    const float* __restrict__ re_w0, const float* __restrict__ re_b0,
    const float* __restrict__ re_b1, const float* __restrict__ re_b2,
    const f16* __restrict__ re1T_h, const f16* __restrict__ re1T_l,
    const f16* __restrict__ re2T_h, const f16* __restrict__ re2T_l,
    float* __restrict__ pe, f16* __restrict__ pe_h, f16* __restrict__ pe_l,
    f16* __restrict__ rel_h, f16* __restrict__ rel_l) {
  __shared__ MainLds u;
  __shared__ float xt6[6][128];
  __shared__ float w0s6[6][128];
  __shared__ float sb0[128];

  const int bid = blockIdx.x, t = threadIdx.x;
  const int lane = t & 63, w = t >> 6;
  const int l16 = lane & 15, l4 = lane >> 4;
  const int f = t & 127, g = t >> 7;

  auto stageB = [&](const f16* gh, const f16* gl) {
    #pragma unroll
    for (int rb = 0; rb < 32; rb += 4) {
      const int r0w = w * 32 + rb;
      const int row = r0w + l4;
      const int sc = (l16 ^ (row & 7)) * 8;
      gl16(gh + (size_t)row * 128 + sc, &u.g.Bh[r0w * 128]);
      gl16(gl + (size_t)row * 128 + sc, &u.g.Bl[r0w * 128]);
    }
  };

  // ---------------- particle_encode -----------------------------------------
  {
    const int r0 = bid * 16;
    for (int i = t; i < 10 * NF_; i += 256) u.v.w0s[i >> 7][i & 127] = pe_w0[i];
    if (t < NF_) { u.v.b0s[t] = pe_b0[t]; u.v.b1s[t] = pe_b1[t]; }
    for (int i = t; i < 160; i += 256) {
      const int r = i / 10, k = i % 10;
      const int gr = r0 + r, b = gr >> 11, n = gr & (N_ - 1);
      u.v.xs[r][k] = (k < 9)
          ? s_delta[(((size_t)b * NH_ + (k / 3)) * N_ + n) * 3 + (k % 3)]
          : a_cur[gr];
    }
    __syncthreads();
    for (int r = g * 8; r < g * 8 + 8; ++r) {
      float a1 = u.v.b0s[f];
      #pragma unroll
      for (int k = 0; k < 10; ++k) a1 = fmaf(u.v.xs[r][k], u.v.w0s[k][f], a1);
      u.v.ht[f][r] = fmaxf(a1, 0.f);
    }
    float acc[8];
    #pragma unroll
    for (int i = 0; i < 8; ++i) acc[i] = u.v.b1s[f];
    for (int h = 0; h < 2; ++h) {
      __syncthreads();
      for (int i = t; i < 64 * NF_; i += 256) u.v.wbuf[i >> 7][i & 127] = pe_w1[h * 64 * NF_ + i];
      __syncthreads();
      for (int k = 0; k < 64; ++k) {
        const float wv = u.v.wbuf[k][f];
        #pragma unroll
        for (int i = 0; i < 2; ++i) {
          const float4 x4 = *reinterpret_cast<const float4*>(&u.v.ht[h * 64 + k][g * 8 + i * 4]);
          acc[i*4+0] = fmaf(x4.x, wv, acc[i*4+0]);
          acc[i*4+1] = fmaf(x4.y, wv, acc[i*4+1]);
          acc[i*4+2] = fmaf(x4.z, wv, acc[i*4+2]);
          acc[i*4+3] = fmaf(x4.w, wv, acc[i*4+3]);
        }
      }
    }
    #pragma unroll
    for (int i = 0; i < 8; ++i) {
      const size_t idx = (size_t)(r0 + g * 8 + i) * NF_ + f;
      const float v = fmaxf(acc[i], 0.f);
      pe[idx] = v;
      const f16 h = (f16)v;
      pe_h[idx] = h; pe_l[idx] = (f16)(v - (float)h);
    }
  }
  __syncthreads();

  // ---------------- relation L1+L2+L3 ---------------------------------------
  {
    const int e0 = bid * 128;
    if (t < 128) {
      const int ge = e0 + t, b = ge >> 14;
      const int rc = recv[ge], sd = send[ge];
      xt6[0][t] = a_cur[(b << 11) + rc];
      xt6[1][t] = a_cur[(b << 11) + sd];
      #pragma unroll
      for (int d = 0; d < 3; ++d)
        xt6[2 + d][t] = s_cur[(size_t)((b << 11) + rc) * 3 + d]
                      - s_cur[(size_t)((b << 11) + sd) * 3 + d];
      xt6[5][t] = ea[ge];
    }
    stageB(re1T_h, re1T_l);
    for (int i = t; i < 6 * 128; i += 256) w0s6[i >> 7][i & 127] = re_w0[i];
    if (t < 128) sb0[t] = re_b0[t];
    __syncthreads();
    // L1 (K=6) -> h1 in swizzled LDS A-tile
    {
      float wreg[6];
      #pragma unroll
      for (int k = 0; k < 6; ++k) wreg[k] = w0s6[k][f];
      const float b0v = sb0[f];
      for (int r = g * 64; r < g * 64 + 64; ++r) {
        float a1 = b0v;
        #pragma unroll
        for (int k = 0; k < 6; ++k) a1 = fmaf(xt6[k][r], wreg[k], a1);
        a1 = fmaxf(a1, 0.f);
        const int off = r * 128 + ((((f >> 3)) ^ (r & 7)) * 8) + (f & 7);
        const f16 h = (f16)a1;
        u.g.Ah[off] = h; u.g.Al[off] = (f16)(a1 - (float)h);
      }
    }
    __syncthreads();
    f32x4 acc[8][2];
    {
      const float bv0 = re_b1[w * 32 + l16], bv1 = re_b1[w * 32 + 16 + l16];
      #pragma unroll
      for (int m = 0; m < 8; ++m) {
        acc[m][0] = (f32x4){bv0, bv0, bv0, bv0};
        acc[m][1] = (f32x4){bv1, bv1, bv1, bv1};
      }
    }
    mfma_block(u.g.Ah, u.g.Al, u.g.Bh, u.g.Bl, acc, lane, w);
    __syncthreads();
    frags_to_lds(acc, u.g.Ah, u.g.Al, lane, w);
    stageB(re2T_h, re2T_l);
    {
      const float bv0 = re_b2[w * 32 + l16], bv1 = re_b2[w * 32 + 16 + l16];
      #pragma unroll
      for (int m = 0; m < 8; ++m) {
        acc[m][0] = (f32x4){bv0, bv0, bv0, bv0};
        acc[m][1] = (f32x4){bv1, bv1, bv1, bv1};
      }
    }
    __syncthreads();
    mfma_block(u.g.Ah, u.g.Al, u.g.Bh, u.g.Bl, acc, lane, w);
    __syncthreads();
    frags_to_lds(acc, u.g.Ah, u.g.Al, lane, w);
    __syncthreads();
    // copy rel tile (swizzled layout preserved) LDS -> global
    // each (row, hf) half-row = 64 f16 = 8 float4  (R4 bug: copied only 4)
    {
      const int row = t >> 1, hf = t & 1;
      const float4* sA = (const float4*)&u.g.Ah[row * 128 + hf * 64];
      const float4* sL = (const float4*)&u.g.Al[row * 128 + hf * 64];
      float4* dA = (float4*)&rel_h[(size_t)(e0 + row) * 128 + hf * 64];
      float4* dL = (float4*)&rel_l[(size_t)(e0 + row) * 128 + hf * 64];
      #pragma unroll
      for (int j = 0; j < 8; ++j) { dA[j] = sA[j]; dL[j] = sL[j]; }
    }
  }
}

// ---------------------------------------------------------------------------
// Launch 3/5/7: erel GEMM (K=384, 3 chunks) + atomic scatter-add into agg.
// ---------------------------------------------------------------------------
__global__ __launch_bounds__(256, 1) void k_erel(
    const f16* __restrict__ rel_h, const f16* __restrict__ rel_l,
    const f16* __restrict__ src_h, const f16* __restrict__ src_l,
    const int* __restrict__ recv, const int* __restrict__ send,
    const f16* __restrict__ rpT_h, const f16* __restrict__ rpT_l,
    const float* __restrict__ rp_b, float* __restrict__ agg) {
  __shared__ GemmLds u;
  __shared__ int eidx0[128], eidx1[128];
  const int bid = blockIdx.x, t = threadIdx.x;
  const int lane = t & 63, w = t >> 6;
  const int l16 = lane & 15, l4 = lane >> 4;
  const int e0 = bid * 128;
  const int b = bid >> 7;
  if (t < 128) eidx0[t] = recv[e0 + t];
  else         eidx1[t - 128] = send[e0 + t - 128];
  f32x4 acc[8][2];
  {
    const float bv0 = rp_b[w * 32 + l16], bv1 = rp_b[w * 32 + 16 + l16];
    #pragma unroll
    for (int m = 0; m < 8; ++m) {
      acc[m][0] = (f32x4){bv0, bv0, bv0, bv0};
      acc[m][1] = (f32x4){bv1, bv1, bv1, bv1};
    }
  }
  #pragma unroll 1
  for (int ch = 0; ch < 3; ++ch) {
    __syncthreads();
    #pragma unroll
    for (int rb = 0; rb < 32; rb += 4) {
      const int r0w = w * 32 + rb;
      const int row = r0w + l4;
      const int ge = e0 + row;
      if (ch == 0) {
        gl16(rel_h + (size_t)ge * 128 + l16 * 8, &u.Ah[r0w * 128]);
        gl16(rel_l + (size_t)ge * 128 + l16 * 8, &u.Al[r0w * 128]);
      } else {
        const int node = (ch == 1) ? eidx0[row] : eidx1[row];
        const size_t ao = ((size_t)(b << 11) + node) * 128 + ((l16 ^ (row & 7)) * 8);
        gl16(src_h + ao, &u.Ah[r0w * 128]);
        gl16(src_l + ao, &u.Al[r0w * 128]);
      }
      const int sc = (l16 ^ (row & 7)) * 8;
      gl16(rpT_h + (size_t)row * 384 + ch * 128 + sc, &u.Bh[r0w * 128]);
      gl16(rpT_l + (size_t)row * 384 + ch * 128 + sc, &u.Bl[r0w * 128]);
    }
    __syncthreads();
    mfma_block(u.Ah, u.Al, u.Bh, u.Bl, acc, lane, w);
  }
  #pragma unroll
  for (int m = 0; m < 8; ++m)
    #pragma unroll
    for (int nf = 0; nf < 2; ++nf)
      #pragma unroll
      for (int i = 0; i < 4; ++i) {
        const float v = fmaxf(acc[m][nf][i], 0.f);
        const int row = m * 16 + l4 * 4 + i;
        const int col = w * 32 + nf * 16 + l16;
        const int rc = eidx0[row];
        atomicAdd(&agg[((size_t)(b << 11) + rc) * NF_ + col], v);
      }
}

// ---------------------------------------------------------------------------
// Launch 4/6/8: effect update MLP (16 nodes/block, K=256, vector fp32).
// Re-zeros its agg rows after reading (safe: next k_erel is a later launch).
// ---------------------------------------------------------------------------
__global__ __launch_bounds__(256) void k_update(
    const float* __restrict__ pe, float* __restrict__ agg,
    const float* __restrict__ src_f,
    const float* __restrict__ pp_w, const float* __restrict__ pp_b,
    float* __restrict__ dst_f, f16* __restrict__ dst_h, f16* __restrict__ dst_l) {
  __shared__ alignas(16) float wbuf[64][NF_];
  __shared__ alignas(16) float xt[NF_][20];
  const int t = threadIdx.x, f = t & 127, g = t >> 7;
  const int r0 = blockIdx.x * 16;
  float acc[8];
  {
    const float bias = pp_b[f];
    #pragma unroll
    for (int i = 0; i < 8; ++i) acc[i] = bias;
  }
  for (int c = 0; c < 2; ++c) {
    __syncthreads();
    {
      const int e = t >> 4, k0 = (t & 15) * 8;
      float* srcp = (float*)((c ? agg : pe) + (size_t)(r0 + e) * NF_ + k0);
      #pragma unroll
      for (int j = 0; j < 2; ++j) {
        const float4 v = *reinterpret_cast<const float4*>(srcp + j * 4);
        xt[k0 + j*4 + 0][e] = v.x;
        xt[k0 + j*4 + 1][e] = v.y;
        xt[k0 + j*4 + 2][e] = v.z;
        xt[k0 + j*4 + 3][e] = v.w;
      }
      if (c == 1) {   // re-zero agg rows for the next step's accumulation
        #pragma unroll
        for (int j = 0; j < 2; ++j)
          *reinterpret_cast<float4*>(srcp + j * 4) = make_float4(0.f, 0.f, 0.f, 0.f);
      }
    }
    #pragma unroll 1
    for (int h = 0; h < 2; ++h) {
      __syncthreads();
      for (int i = t; i < 64 * NF_; i += 256)
        wbuf[i >> 7][i & 127] = pp_w[(size_t)(c * NF_ + h * 64) * NF_ + i];
      __syncthreads();
      for (int k = 0; k < 64; ++k) {
        const float wv = wbuf[k][f];
        const int ka = h * 64 + k;
        #pragma unroll
        for (int i = 0; i < 2; ++i) {
          const float4 x4 = *reinterpret_cast<const float4*>(&xt[ka][g * 8 + i * 4]);
          acc[i*4+0] = fmaf(x4.x, wv, acc[i*4+0]);
          acc[i*4+1] = fmaf(x4.y, wv, acc[i*4+1]);
          acc[i*4+2] = fmaf(x4.z, wv, acc[i*4+2]);
          acc[i*4+3] = fmaf(x4.w, wv, acc[i*4+3]);
        }
      }
    }
  }
  #pragma unroll
  for (int i = 0; i < 8; ++i) {
    const size_t idx = (size_t)(r0 + g * 8 + i) * NF_ + f;
    const float v = fmaxf(acc[i] + src_f[idx], 0.f);
    dst_f[idx] = v;
    const f16 h = (f16)v;
    dst_h[idx] = h; dst_l[idx] = (f16)(v - (float)h);
  }
}

// ---------------------------------------------------------------------------
// Launch 9: predict.
// ---------------------------------------------------------------------------
__global__ __launch_bounds__(256) void k_predict(
    const float* __restrict__ eff, const float* __restrict__ s_cur,
    const float* __restrict__ w0, const float* __restrict__ b0,
    const float* __restrict__ w1, const float* __restrict__ b1,
    float* __restrict__ out) {
  __shared__ alignas(16) float wbuf[64][NF_];
  __shared__ alignas(16) float xt[NF_][20];
  __shared__ alignas(16) float ht[NF_][20];
  __shared__ float w1s[NF_][4];
  const int t = threadIdx.x, f = t & 127, g = t >> 7;
  const int r0 = blockIdx.x * 16;
  for (int i = t; i < NF_ * 3; i += 256) w1s[i / 3][i % 3] = w1[i];
  {
    const int e = t >> 4, k0 = (t & 15) * 8;
    const float* src = eff + (size_t)(r0 + e) * NF_ + k0;
    #pragma unroll
    for (int j = 0; j < 2; ++j) {
      const float4 v = *reinterpret_cast<const float4*>(src + j * 4);
      xt[k0 + j*4 + 0][e] = v.x;
      xt[k0 + j*4 + 1][e] = v.y;
      xt[k0 + j*4 + 2][e] = v.z;
      xt[k0 + j*4 + 3][e] = v.w;
    }
  }
  float acc[8];
  {
    const float bias = b0[f];
    #pragma unroll
    for (int i = 0; i < 8; ++i) acc[i] = bias;
  }
  for (int h = 0; h < 2; ++h) {
    __syncthreads();
    for (int i = t; i < 64 * NF_; i += 256) wbuf[i >> 7][i & 127] = w0[h * 64 * NF_ + i];
    __syncthreads();
    for (int k = 0; k < 64; ++k) {
      const float wv = wbuf[k][f];
      const int ka = h * 64 + k;
      #pragma unroll
      for (int i = 0; i < 2; ++i) {
        const float4 x4 = *reinterpret_cast<const float4*>(&xt[ka][g * 8 + i * 4]);
        acc[i*4+0] = fmaf(x4.x, wv, acc[i*4+0]);
        acc[i*4+1] = fmaf(x4.y, wv, acc[i*4+1]);
        acc[i*4+2] = fmaf(x4.z, wv, acc[i*4+2]);
        acc[i*4+3] = fmaf(x4.w, wv, acc[i*4+3]);
      }
    }
  }
  #pragma unroll
  for (int i = 0; i < 8; ++i) ht[f][g * 8 + i] = fmaxf(acc[i], 0.f);
  __syncthreads();
  if (t < 48) {
    const int r = t / 3, d = t % 3;
    float a2 = b1[d];
    for (int k = 0; k < NF_; ++k) a2 = fmaf(ht[k][r], w1s[k][d], a2);
    const int gr = r0 + r;
    out[(size_t)gr * 3 + d] = a2 + s_cur[(size_t)gr * 3 + d];
  }
}

// ---------------------------------------------------------------------------
extern "C" void kernel_launch(void* const* d_in, const int* in_sizes, int n_in,
                              void* d_out, int out_size, void* d_ws, size_t ws_size,
                              hipStream_t stream) {
  (void)in_sizes; (void)n_in; (void)out_size; (void)ws_size;
  const float* a_cur   = (const float*)d_in[0];
  const float* s_cur   = (const float*)d_in[1];
  const float* s_delta = (const float*)d_in[2];
  const float* Rr      = (const float*)d_in[3];
  const float* Rs      = (const float*)d_in[4];
  const float* ea      = (const float*)d_in[5];
  const float* pe_w0 = (const float*)d_in[6];
  const float* pe_b0 = (const float*)d_in[7];
  const float* pe_w1 = (const float*)d_in[8];
  const float* pe_b1 = (const float*)d_in[9];
  const float* re_w0 = (const float*)d_in[10];
  const float* re_b0 = (const float*)d_in[11];
  const float* re_w1 = (const float*)d_in[12];
  const float* re_b1 = (const float*)d_in[13];
  const float* re_w2 = (const float*)d_in[14];
  const float* re_b2 = (const float*)d_in[15];
  const float* rp_w  = (const float*)d_in[16];
  const float* rp_b  = (const float*)d_in[17];
  const float* pp_w  = (const float*)d_in[18];
  const float* pp_b  = (const float*)d_in[19];
  const float* pr_w0 = (const float*)d_in[20];
  const float* pr_b0 = (const float*)d_in[21];
  const float* pr_w1 = (const float*)d_in[22];
  const float* pr_b1 = (const float*)d_in[23];
  float* out = (float*)d_out;

  uint8_t* wp = (uint8_t*)d_ws;
  auto alloc = [&](size_t bytes) {
    void* p = (void*)wp;
    wp += (bytes + 255) & ~(size_t)255;
    return p;
  };
  int* recv   = (int*)alloc(EDGES * 4);
  int* send   = (int*)alloc(EDGES * 4);
  float* pe   = (float*)alloc((size_t)NODES * NF_ * 4);
  f16* pe_h   = (f16*)alloc((size_t)NODES * NF_ * 2);
  f16* pe_l   = (f16*)alloc((size_t)NODES * NF_ * 2);
  float* eff  = (float*)alloc((size_t)NODES * NF_ * 4);
  f16* eff_h  = (f16*)alloc((size_t)NODES * NF_ * 2);
  f16* eff_l  = (f16*)alloc((size_t)NODES * NF_ * 2);
  float* agg  = (float*)alloc((size_t)NODES * NF_ * 4);
  f16* rel_h  = (f16*)alloc((size_t)EDGES * NF_ * 2);
  f16* rel_l  = (f16*)alloc((size_t)EDGES * NF_ * 2);
  f16* rpT_h  = (f16*)alloc(128 * 384 * 2);
  f16* rpT_l  = (f16*)alloc(128 * 384 * 2);
  f16* re1T_h = (f16*)alloc(128 * 128 * 2);
  f16* re1T_l = (f16*)alloc(128 * 128 * 2);
  f16* re2T_h = (f16*)alloc(128 * 128 * 2);
  f16* re2T_l = (f16*)alloc(128 * 128 * 2);

  k_prep<<<PREP_EXB0 + (2 * EDGES) / 4, 256, 0, stream>>>(
      Rr, Rs, rp_w, re_w1, re_w2, recv, send,
      rpT_h, rpT_l, re1T_h, re1T_l, re2T_h, re2T_l, (float4*)agg);

  k_pre<<<256, 256, 0, stream>>>(
      a_cur, s_cur, s_delta, ea, recv, send,
      pe_w0, pe_b0, pe_w1, pe_b1, re_w0, re_b0, re_b1, re_b2,
      re1T_h, re1T_l, re2T_h, re2T_l,
      pe, pe_h, pe_l, rel_h, rel_l);

  const float* esrc = pe;
  const f16* esrc_h = pe_h;
  const f16* esrc_l = pe_l;
  for (int s = 0; s < PSTEP_; ++s) {
    k_erel<<<EDGES / 128, 256, 0, stream>>>(rel_h, rel_l, esrc_h, esrc_l,
                                            recv, send, rpT_h, rpT_l, rp_b, agg);
    k_update<<<NODES / 16, 256, 0, stream>>>(pe, agg, esrc, pp_w, pp_b,
                                             eff, eff_h, eff_l);
    esrc = eff; esrc_h = eff_h; esrc_l = eff_l;
  }

  k_predict<<<NODES / 16, 256, 0, stream>>>(eff, s_cur, pr_w0, pr_b0,
                                            pr_w1, pr_b1, out);
}

// Round 6
// 692.454 us; speedup vs baseline: 1.3032x; 1.0139x over previous
//
#include <hip/hip_runtime.h>
#include <hip/hip_bf16.h>
#include <stdint.h>

#define B_ 2
#define N_ 2048      // 2^11
#define R_ 16384     // 2^14
#define NF_ 128
#define NH_ 3
#define PSTEP_ 3
#define EDGES (B_ * R_)    // 32768
#define NODES (B_ * N_)    // 4096
#define MAXDEG 64
#define PREP_EXB0 1024

typedef _Float16 f16;
typedef _Float16 f16x4 __attribute__((ext_vector_type(4)));
typedef float f32x4 __attribute__((ext_vector_type(4)));

struct GemmLds { f16 Ah[128 * 128], Al[128 * 128], Bh[128 * 128], Bl[128 * 128]; }; // 128 KB
struct VecLds {
  float wbuf[64][NF_];          // 32 KB
  float xt[NF_][20];            // 10 KB
  float ht[NF_][20];            // 10 KB
  float w0s[10][NF_];
  float b0s[NF_], b1s[NF_];
  float xs[16][10];
  float w1s[NF_][4];
};
union MainLds { GemmLds g; VecLds v; };

// ---------------------------------------------------------------------------
__device__ __forceinline__ void gl16(const f16* g, f16* l) {
  typedef const __attribute__((address_space(1))) uint32_t* gas_t;
  typedef __attribute__((address_space(3))) uint32_t* las_t;
  __builtin_amdgcn_global_load_lds((gas_t)(const void*)g, (las_t)(void*)l, 16, 0, 0);
}

// 128x128x128 split-f16 MFMA block GEMM step (A,B staged in LDS, swizzled).
__device__ __forceinline__ void mfma_block(const f16* Ah, const f16* Al,
                                           const f16* Bh, const f16* Bl,
                                           f32x4 (&acc)[8][2], int lane, int w) {
  const int l16 = lane & 15, l4 = lane >> 4;
  #pragma unroll 1
  for (int kk = 0; kk < 8; ++kk) {
    const int c16 = kk * 2 + (l4 >> 1);
    const int sub = (l4 & 1) * 4;
    f16x4 bh[2], bl[2];
    #pragma unroll
    for (int nf = 0; nf < 2; ++nf) {
      const int n = w * 32 + nf * 16 + l16;
      const int off = n * 128 + ((c16 ^ (n & 7)) * 8) + sub;
      bh[nf] = *(const f16x4*)&Bh[off];
      bl[nf] = *(const f16x4*)&Bl[off];
    }
    #pragma unroll
    for (int m = 0; m < 8; ++m) {
      const int r = m * 16 + l16;
      const int off = r * 128 + ((c16 ^ (r & 7)) * 8) + sub;
      const f16x4 ah = *(const f16x4*)&Ah[off];
      const f16x4 al = *(const f16x4*)&Al[off];
      #pragma unroll
      for (int nf = 0; nf < 2; ++nf) {
        acc[m][nf] = __builtin_amdgcn_mfma_f32_16x16x16f16(ah, bh[nf], acc[m][nf], 0, 0, 0);
        acc[m][nf] = __builtin_amdgcn_mfma_f32_16x16x16f16(ah, bl[nf], acc[m][nf], 0, 0, 0);
        acc[m][nf] = __builtin_amdgcn_mfma_f32_16x16x16f16(al, bh[nf], acc[m][nf], 0, 0, 0);
      }
    }
  }
}

// relu + split-f16 frag write back into swizzled LDS A-tile.
__device__ __forceinline__ void frags_to_lds(f32x4 (&acc)[8][2], f16* Ah, f16* Al,
                                             int lane, int w) {
  const int l16 = lane & 15, l4 = lane >> 4;
  #pragma unroll
  for (int m = 0; m < 8; ++m)
    #pragma unroll
    for (int nf = 0; nf < 2; ++nf)
      #pragma unroll
      for (int i = 0; i < 4; ++i) {
        const float v = fmaxf(acc[m][nf][i], 0.f);
        const int row = m * 16 + l4 * 4 + i;
        const int col = w * 32 + nf * 16 + l16;
        const int off = row * 128 + (((col >> 3) ^ (row & 7)) * 8) + (col & 7);
        const f16 h = (f16)v;
        Ah[off] = h; Al[off] = (f16)(v - (float)h);
      }
}

// ---------------------------------------------------------------------------
// Launch 1: zero CSR counts + weight convert/transpose + extract indices.
// ---------------------------------------------------------------------------
__global__ __launch_bounds__(256) void k_prep(
    const float* __restrict__ Rr, const float* __restrict__ Rs,
    const float* __restrict__ rp_w, const float* __restrict__ re_w1,
    const float* __restrict__ re_w2,
    int* __restrict__ recv, int* __restrict__ send,
    f16* __restrict__ rpT_h, f16* __restrict__ rpT_l,
    f16* __restrict__ re1T_h, f16* __restrict__ re1T_l,
    f16* __restrict__ re2T_h, f16* __restrict__ re2T_l,
    int* __restrict__ counts) {
  const int bid = blockIdx.x, t = threadIdx.x;
  if (bid < 16) {                          // zero counts (4096 ints)
    counts[bid * 256 + t] = 0;
  } else if (bid < 336) {                  // weight convert (81920 elements)
    const int i = (bid - 16) * 256 + t;
    const int S1 = 384 * 128, S2 = S1 + 128 * 128, S3 = S2 + 128 * 128;
    if (i < S1) {
      const int k = i >> 7, n = i & 127;
      const float v = rp_w[i];
      const f16 h = (f16)v;
      rpT_h[n * 384 + k] = h; rpT_l[n * 384 + k] = (f16)(v - (float)h);
    } else if (i < S2) {
      const int j = i - S1, k = j >> 7, n = j & 127;
      const float v = re_w1[j];
      const f16 h = (f16)v;
      re1T_h[n * 128 + k] = h; re1T_l[n * 128 + k] = (f16)(v - (float)h);
    } else if (i < S3) {
      const int j = i - S2, k = j >> 7, n = j & 127;
      const float v = re_w2[j];
      const f16 h = (f16)v;
      re2T_h[n * 128 + k] = h; re2T_l[n * 128 + k] = (f16)(v - (float)h);
    }
  } else if (bid >= PREP_EXB0) {           // extract: one wave per one-hot row
    const int wid = (bid - PREP_EXB0) * 4 + (t >> 6);
    const int lane = t & 63;
    const bool isR = wid < EDGES;
    const int row = isR ? wid : wid - EDGES;
    const float4* p = reinterpret_cast<const float4*>((isR ? Rr : Rs) + (size_t)row * N_);
    int found = 0;
    #pragma unroll 1
    for (int it = 0; it < N_ / 256; ++it) {
      const float4 v = p[it * 64 + lane];
      const int base = (it * 64 + lane) * 4;
      bool hit = false;
      if (v.x != 0.f) { found = base;     hit = true; }
      if (v.y != 0.f) { found = base + 1; hit = true; }
      if (v.z != 0.f) { found = base + 2; hit = true; }
      if (v.w != 0.f) { found = base + 3; hit = true; }
      if (__any(hit)) break;
    }
    #pragma unroll
    for (int off = 32; off > 0; off >>= 1)
      found = max(found, __shfl_down(found, off, 64));
    if (lane == 0) (isR ? recv : send)[row] = found;
  }
}

// ---------------------------------------------------------------------------
// Launch 2: CSR bucket fill + particle_encode (16 nodes/block) + relation
// L1+L2+L3 fused (128 edges/block).  256 blocks.
// ---------------------------------------------------------------------------
__global__ __launch_bounds__(256, 1) void k_pre(
    const float* __restrict__ a_cur, const float* __restrict__ s_cur,
    const float* __restrict__ s_delta, const float* __restrict__ ea,
    const int* __restrict__ recv, const int* __restrict__ send,
    const float* __restrict__ pe_w0, const float* __restrict__ pe_b0,
    const float* __restrict__ pe_w1, const float* __restrict__ pe_b1,
    const float* __restrict__ re_w0, const float* __restrict__ re_b0,
    const float* __restrict__ re_b1, const float* __restrict__ re_b2,
    const f16* __restrict__ re1T_h, const f16* __restrict__ re1T_l,
    const f16* __restrict__ re2T_h, const f16* __restrict__ re2T_l,
    float* __restrict__ pe, f16* __restrict__ pe_h, f16* __restrict__ pe_l,
    f16* __restrict__ rel_h, f16* __restrict__ rel_l,
    int* __restrict__ counts, int* __restrict__ bucket) {
  __shared__ MainLds u;
  __shared__ float xt6[6][128];
  __shared__ float w0s6[6][128];
  __shared__ float sb0[128];

  const int bid = blockIdx.x, t = threadIdx.x;
  const int lane = t & 63, w = t >> 6;
  const int l16 = lane & 15, l4 = lane >> 4;
  const int f = t & 127, g = t >> 7;

  // ---------------- CSR bucket fill (for k_update's gather-agg) -------------
  {
    const int e = bid * 256 + t;
    if (e < EDGES) {
      const int gnode = (e >> 14) * N_ + recv[e];
      const int pos = atomicAdd(&counts[gnode], 1);
      if (pos < MAXDEG) bucket[gnode * MAXDEG + pos] = e;
    }
  }

  auto stageB = [&](const f16* gh, const f16* gl) {
    #pragma unroll
    for (int rb = 0; rb < 32; rb += 4) {
      const int r0w = w * 32 + rb;
      const int row = r0w + l4;
      const int sc = (l16 ^ (row & 7)) * 8;
      gl16(gh + (size_t)row * 128 + sc, &u.g.Bh[r0w * 128]);
      gl16(gl + (size_t)row * 128 + sc, &u.g.Bl[r0w * 128]);
    }
  };

  // ---------------- particle_encode -----------------------------------------
  {
    const int r0 = bid * 16;
    for (int i = t; i < 10 * NF_; i += 256) u.v.w0s[i >> 7][i & 127] = pe_w0[i];
    if (t < NF_) { u.v.b0s[t] = pe_b0[t]; u.v.b1s[t] = pe_b1[t]; }
    for (int i = t; i < 160; i += 256) {
      const int r = i / 10, k = i % 10;
      const int gr = r0 + r, b = gr >> 11, n = gr & (N_ - 1);
      u.v.xs[r][k] = (k < 9)
          ? s_delta[(((size_t)b * NH_ + (k / 3)) * N_ + n) * 3 + (k % 3)]
          : a_cur[gr];
    }
    __syncthreads();
    for (int r = g * 8; r < g * 8 + 8; ++r) {
      float a1 = u.v.b0s[f];
      #pragma unroll
      for (int k = 0; k < 10; ++k) a1 = fmaf(u.v.xs[r][k], u.v.w0s[k][f], a1);
      u.v.ht[f][r] = fmaxf(a1, 0.f);
    }
    float acc[8];
    #pragma unroll
    for (int i = 0; i < 8; ++i) acc[i] = u.v.b1s[f];
    for (int h = 0; h < 2; ++h) {
      __syncthreads();
      for (int i = t; i < 64 * NF_; i += 256) u.v.wbuf[i >> 7][i & 127] = pe_w1[h * 64 * NF_ + i];
      __syncthreads();
      for (int k = 0; k < 64; ++k) {
        const float wv = u.v.wbuf[k][f];
        #pragma unroll
        for (int i = 0; i < 2; ++i) {
          const float4 x4 = *reinterpret_cast<const float4*>(&u.v.ht[h * 64 + k][g * 8 + i * 4]);
          acc[i*4+0] = fmaf(x4.x, wv, acc[i*4+0]);
          acc[i*4+1] = fmaf(x4.y, wv, acc[i*4+1]);
          acc[i*4+2] = fmaf(x4.z, wv, acc[i*4+2]);
          acc[i*4+3] = fmaf(x4.w, wv, acc[i*4+3]);
        }
      }
    }
    #pragma unroll
    for (int i = 0; i < 8; ++i) {
      const size_t idx = (size_t)(r0 + g * 8 + i) * NF_ + f;
      const float v = fmaxf(acc[i], 0.f);
      pe[idx] = v;
      const f16 h = (f16)v;
      pe_h[idx] = h; pe_l[idx] = (f16)(v - (float)h);
    }
  }
  __syncthreads();

  // ---------------- relation L1+L2+L3 ---------------------------------------
  {
    const int e0 = bid * 128;
    if (t < 128) {
      const int ge = e0 + t, b = ge >> 14;
      const int rc = recv[ge], sd = send[ge];
      xt6[0][t] = a_cur[(b << 11) + rc];
      xt6[1][t] = a_cur[(b << 11) + sd];
      #pragma unroll
      for (int d = 0; d < 3; ++d)
        xt6[2 + d][t] = s_cur[(size_t)((b << 11) + rc) * 3 + d]
                      - s_cur[(size_t)((b << 11) + sd) * 3 + d];
      xt6[5][t] = ea[ge];
    }
    stageB(re1T_h, re1T_l);
    for (int i = t; i < 6 * 128; i += 256) w0s6[i >> 7][i & 127] = re_w0[i];
    if (t < 128) sb0[t] = re_b0[t];
    __syncthreads();
    // L1 (K=6) -> h1 in swizzled LDS A-tile
    {
      float wreg[6];
      #pragma unroll
      for (int k = 0; k < 6; ++k) wreg[k] = w0s6[k][f];
      const float b0v = sb0[f];
      for (int r = g * 64; r < g * 64 + 64; ++r) {
        float a1 = b0v;
        #pragma unroll
        for (int k = 0; k < 6; ++k) a1 = fmaf(xt6[k][r], wreg[k], a1);
        a1 = fmaxf(a1, 0.f);
        const int off = r * 128 + ((((f >> 3)) ^ (r & 7)) * 8) + (f & 7);
        const f16 h = (f16)a1;
        u.g.Ah[off] = h; u.g.Al[off] = (f16)(a1 - (float)h);
      }
    }
    __syncthreads();
    f32x4 acc[8][2];
    {
      const float bv0 = re_b1[w * 32 + l16], bv1 = re_b1[w * 32 + 16 + l16];
      #pragma unroll
      for (int m = 0; m < 8; ++m) {
        acc[m][0] = (f32x4){bv0, bv0, bv0, bv0};
        acc[m][1] = (f32x4){bv1, bv1, bv1, bv1};
      }
    }
    mfma_block(u.g.Ah, u.g.Al, u.g.Bh, u.g.Bl, acc, lane, w);
    __syncthreads();
    frags_to_lds(acc, u.g.Ah, u.g.Al, lane, w);
    stageB(re2T_h, re2T_l);
    {
      const float bv0 = re_b2[w * 32 + l16], bv1 = re_b2[w * 32 + 16 + l16];
      #pragma unroll
      for (int m = 0; m < 8; ++m) {
        acc[m][0] = (f32x4){bv0, bv0, bv0, bv0};
        acc[m][1] = (f32x4){bv1, bv1, bv1, bv1};
      }
    }
    __syncthreads();
    mfma_block(u.g.Ah, u.g.Al, u.g.Bh, u.g.Bl, acc, lane, w);
    __syncthreads();
    frags_to_lds(acc, u.g.Ah, u.g.Al, lane, w);
    __syncthreads();
    // copy rel tile (swizzled layout preserved) LDS -> global: 8 f4/half-row
    {
      const int row = t >> 1, hf = t & 1;
      const float4* sA = (const float4*)&u.g.Ah[row * 128 + hf * 64];
      const float4* sL = (const float4*)&u.g.Al[row * 128 + hf * 64];
      float4* dA = (float4*)&rel_h[(size_t)(e0 + row) * 128 + hf * 64];
      float4* dL = (float4*)&rel_l[(size_t)(e0 + row) * 128 + hf * 64];
      #pragma unroll
      for (int j = 0; j < 8; ++j) { dA[j] = sA[j]; dL[j] = sL[j]; }
    }
  }
}

// ---------------------------------------------------------------------------
// Launch 3/5/7: erel GEMM (K=384, 3 chunks) -> e_rel (f32, streamed store).
// ---------------------------------------------------------------------------
__global__ __launch_bounds__(256, 1) void k_erel(
    const f16* __restrict__ rel_h, const f16* __restrict__ rel_l,
    const f16* __restrict__ src_h, const f16* __restrict__ src_l,
    const int* __restrict__ recv, const int* __restrict__ send,
    const f16* __restrict__ rpT_h, const f16* __restrict__ rpT_l,
    const float* __restrict__ rp_b, float* __restrict__ e_rel) {
  __shared__ GemmLds u;
  __shared__ int eidx0[128], eidx1[128];
  const int bid = blockIdx.x, t = threadIdx.x;
  const int lane = t & 63, w = t >> 6;
  const int l16 = lane & 15, l4 = lane >> 4;
  const int e0 = bid * 128;
  const int b = bid >> 7;
  if (t < 128) eidx0[t] = recv[e0 + t];
  else         eidx1[t - 128] = send[e0 + t - 128];
  f32x4 acc[8][2];
  {
    const float bv0 = rp_b[w * 32 + l16], bv1 = rp_b[w * 32 + 16 + l16];
    #pragma unroll
    for (int m = 0; m < 8; ++m) {
      acc[m][0] = (f32x4){bv0, bv0, bv0, bv0};
      acc[m][1] = (f32x4){bv1, bv1, bv1, bv1};
    }
  }
  #pragma unroll 1
  for (int ch = 0; ch < 3; ++ch) {
    __syncthreads();
    #pragma unroll
    for (int rb = 0; rb < 32; rb += 4) {
      const int r0w = w * 32 + rb;
      const int row = r0w + l4;
      const int ge = e0 + row;
      if (ch == 0) {
        gl16(rel_h + (size_t)ge * 128 + l16 * 8, &u.Ah[r0w * 128]);
        gl16(rel_l + (size_t)ge * 128 + l16 * 8, &u.Al[r0w * 128]);
      } else {
        const int node = (ch == 1) ? eidx0[row] : eidx1[row];
        const size_t ao = ((size_t)(b << 11) + node) * 128 + ((l16 ^ (row & 7)) * 8);
        gl16(src_h + ao, &u.Ah[r0w * 128]);
        gl16(src_l + ao, &u.Al[r0w * 128]);
      }
      const int sc = (l16 ^ (row & 7)) * 8;
      gl16(rpT_h + (size_t)row * 384 + ch * 128 + sc, &u.Bh[r0w * 128]);
      gl16(rpT_l + (size_t)row * 384 + ch * 128 + sc, &u.Bl[r0w * 128]);
    }
    __syncthreads();
    mfma_block(u.Ah, u.Al, u.Bh, u.Bl, acc, lane, w);
  }
  #pragma unroll
  for (int m = 0; m < 8; ++m)
    #pragma unroll
    for (int nf = 0; nf < 2; ++nf)
      #pragma unroll
      for (int i = 0; i < 4; ++i) {
        const float v = fmaxf(acc[m][nf][i], 0.f);
        const int row = e0 + m * 16 + l4 * 4 + i;
        const int col = w * 32 + nf * 16 + l16;
        e_rel[(size_t)row * NF_ + col] = v;
      }
}

// ---------------------------------------------------------------------------
// Launch 4/6/8: gather-agg + effect update MLP (16 nodes/block, K=256).
// final_step!=0: fuse predict (consumes eff in-register; no eff writeback).
// ---------------------------------------------------------------------------
__global__ __launch_bounds__(256) void k_update(
    const float* __restrict__ pe, const float* __restrict__ e_rel,
    const int* __restrict__ counts, const int* __restrict__ bucket,
    const float* __restrict__ src_f,
    const float* __restrict__ pp_w, const float* __restrict__ pp_b,
    float* __restrict__ dst_f, f16* __restrict__ dst_h, f16* __restrict__ dst_l,
    const float* __restrict__ s_cur,
    const float* __restrict__ pr_w0, const float* __restrict__ pr_b0,
    const float* __restrict__ pr_w1, const float* __restrict__ pr_b1,
    float* __restrict__ out, int final_step) {
  __shared__ alignas(16) float wbuf[64][NF_];
  __shared__ alignas(16) float xt[NF_][20];
  __shared__ alignas(16) float ht[NF_][20];
  __shared__ float w1s[NF_][4];
  const int t = threadIdx.x, f = t & 127, g = t >> 7;
  const int r0 = blockIdx.x * 16;
  float acc[8];
  {
    const float bias = pp_b[f];
    #pragma unroll
    for (int i = 0; i < 8; ++i) acc[i] = bias;
  }
  for (int c = 0; c < 2; ++c) {
    __syncthreads();
    {
      const int e = t >> 4, k0 = (t & 15) * 8;
      float s[8];
      if (c == 0) {
        const float* srcp = pe + (size_t)(r0 + e) * NF_ + k0;
        const float4 v0 = *reinterpret_cast<const float4*>(srcp);
        const float4 v1 = *reinterpret_cast<const float4*>(srcp + 4);
        s[0]=v0.x; s[1]=v0.y; s[2]=v0.z; s[3]=v0.w;
        s[4]=v1.x; s[5]=v1.y; s[6]=v1.z; s[7]=v1.w;
      } else {
        #pragma unroll
        for (int i = 0; i < 8; ++i) s[i] = 0.f;
        const int gnode = r0 + e;
        const int cnt = min(counts[gnode], MAXDEG);
        for (int i = 0; i < cnt; ++i) {
          const int ed = bucket[gnode * MAXDEG + i];
          const float4 v0 = *reinterpret_cast<const float4*>(&e_rel[(size_t)ed * NF_ + k0]);
          const float4 v1 = *reinterpret_cast<const float4*>(&e_rel[(size_t)ed * NF_ + k0 + 4]);
          s[0]+=v0.x; s[1]+=v0.y; s[2]+=v0.z; s[3]+=v0.w;
          s[4]+=v1.x; s[5]+=v1.y; s[6]+=v1.z; s[7]+=v1.w;
        }
      }
      #pragma unroll
      for (int i = 0; i < 8; ++i) xt[k0 + i][e] = s[i];
    }
    #pragma unroll 1
    for (int h = 0; h < 2; ++h) {
      __syncthreads();
      for (int i = t; i < 64 * NF_; i += 256)
        wbuf[i >> 7][i & 127] = pp_w[(size_t)(c * NF_ + h * 64) * NF_ + i];
      __syncthreads();
      for (int k = 0; k < 64; ++k) {
        const float wv = wbuf[k][f];
        const int ka = h * 64 + k;
        #pragma unroll
        for (int i = 0; i < 2; ++i) {
          const float4 x4 = *reinterpret_cast<const float4*>(&xt[ka][g * 8 + i * 4]);
          acc[i*4+0] = fmaf(x4.x, wv, acc[i*4+0]);
          acc[i*4+1] = fmaf(x4.y, wv, acc[i*4+1]);
          acc[i*4+2] = fmaf(x4.z, wv, acc[i*4+2]);
          acc[i*4+3] = fmaf(x4.w, wv, acc[i*4+3]);
        }
      }
    }
  }
  if (!final_step) {
    #pragma unroll
    for (int i = 0; i < 8; ++i) {
      const size_t idx = (size_t)(r0 + g * 8 + i) * NF_ + f;
      const float v = fmaxf(acc[i] + src_f[idx], 0.f);
      dst_f[idx] = v;
      const f16 h = (f16)v;
      dst_h[idx] = h; dst_l[idx] = (f16)(v - (float)h);
    }
    return;
  }
  // ---------------- fused predict (final step) ------------------------------
  __syncthreads();     // all xt reads done; reuse xt for eff (transposed)
  #pragma unroll
  for (int i = 0; i < 8; ++i) {
    const size_t idx = (size_t)(r0 + g * 8 + i) * NF_ + f;
    xt[f][g * 8 + i] = fmaxf(acc[i] + src_f[idx], 0.f);
  }
  for (int i = t; i < NF_ * 3; i += 256) w1s[i / 3][i % 3] = pr_w1[i];
  {
    const float bias = pr_b0[f];
    #pragma unroll
    for (int i = 0; i < 8; ++i) acc[i] = bias;
  }
  for (int h = 0; h < 2; ++h) {
    __syncthreads();
    for (int i = t; i < 64 * NF_; i += 256) wbuf[i >> 7][i & 127] = pr_w0[h * 64 * NF_ + i];
    __syncthreads();
    for (int k = 0; k < 64; ++k) {
      const float wv = wbuf[k][f];
      const int ka = h * 64 + k;
      #pragma unroll
      for (int i = 0; i < 2; ++i) {
        const float4 x4 = *reinterpret_cast<const float4*>(&xt[ka][g * 8 + i * 4]);
        acc[i*4+0] = fmaf(x4.x, wv, acc[i*4+0]);
        acc[i*4+1] = fmaf(x4.y, wv, acc[i*4+1]);
        acc[i*4+2] = fmaf(x4.z, wv, acc[i*4+2]);
        acc[i*4+3] = fmaf(x4.w, wv, acc[i*4+3]);
      }
    }
  }
  #pragma unroll
  for (int i = 0; i < 8; ++i) ht[f][g * 8 + i] = fmaxf(acc[i], 0.f);
  __syncthreads();
  if (t < 48) {
    const int r = t / 3, d = t % 3;
    float a2 = pr_b1[d];
    for (int k = 0; k < NF_; ++k) a2 = fmaf(ht[k][r], w1s[k][d], a2);
    const int gr = r0 + r;
    out[(size_t)gr * 3 + d] = a2 + s_cur[(size_t)gr * 3 + d];
  }
}

// ---------------------------------------------------------------------------
extern "C" void kernel_launch(void* const* d_in, const int* in_sizes, int n_in,
                              void* d_out, int out_size, void* d_ws, size_t ws_size,
                              hipStream_t stream) {
  (void)in_sizes; (void)n_in; (void)out_size; (void)ws_size;
  const float* a_cur   = (const float*)d_in[0];
  const float* s_cur   = (const float*)d_in[1];
  const float* s_delta = (const float*)d_in[2];
  const float* Rr      = (const float*)d_in[3];
  const float* Rs      = (const float*)d_in[4];
  const float* ea      = (const float*)d_in[5];
  const float* pe_w0 = (const float*)d_in[6];
  const float* pe_b0 = (const float*)d_in[7];
  const float* pe_w1 = (const float*)d_in[8];
  const float* pe_b1 = (const float*)d_in[9];
  const float* re_w0 = (const float*)d_in[10];
  const float* re_b0 = (const float*)d_in[11];
  const float* re_w1 = (const float*)d_in[12];
  const float* re_b1 = (const float*)d_in[13];
  const float* re_w2 = (const float*)d_in[14];
  const float* re_b2 = (const float*)d_in[15];
  const float* rp_w  = (const float*)d_in[16];
  const float* rp_b  = (const float*)d_in[17];
  const float* pp_w  = (const float*)d_in[18];
  const float* pp_b  = (const float*)d_in[19];
  const float* pr_w0 = (const float*)d_in[20];
  const float* pr_b0 = (const float*)d_in[21];
  const float* pr_w1 = (const float*)d_in[22];
  const float* pr_b1 = (const float*)d_in[23];
  float* out = (float*)d_out;

  uint8_t* wp = (uint8_t*)d_ws;
  auto alloc = [&](size_t bytes) {
    void* p = (void*)wp;
    wp += (bytes + 255) & ~(size_t)255;
    return p;
  };
  int* recv   = (int*)alloc(EDGES * 4);
  int* send   = (int*)alloc(EDGES * 4);
  int* counts = (int*)alloc(NODES * 4);
  int* bucket = (int*)alloc((size_t)NODES * MAXDEG * 4);
  float* pe   = (float*)alloc((size_t)NODES * NF_ * 4);
  f16* pe_h   = (f16*)alloc((size_t)NODES * NF_ * 2);
  f16* pe_l   = (f16*)alloc((size_t)NODES * NF_ * 2);
  float* effA = (float*)alloc((size_t)NODES * NF_ * 4);
  f16* effA_h = (f16*)alloc((size_t)NODES * NF_ * 2);
  f16* effA_l = (f16*)alloc((size_t)NODES * NF_ * 2);
  float* effB = (float*)alloc((size_t)NODES * NF_ * 4);
  f16* effB_h = (f16*)alloc((size_t)NODES * NF_ * 2);
  f16* effB_l = (f16*)alloc((size_t)NODES * NF_ * 2);
  float* e_rel = (float*)alloc((size_t)EDGES * NF_ * 4);
  f16* rel_h  = (f16*)alloc((size_t)EDGES * NF_ * 2);
  f16* rel_l  = (f16*)alloc((size_t)EDGES * NF_ * 2);
  f16* rpT_h  = (f16*)alloc(128 * 384 * 2);
  f16* rpT_l  = (f16*)alloc(128 * 384 * 2);
  f16* re1T_h = (f16*)alloc(128 * 128 * 2);
  f16* re1T_l = (f16*)alloc(128 * 128 * 2);
  f16* re2T_h = (f16*)alloc(128 * 128 * 2);
  f16* re2T_l = (f16*)alloc(128 * 128 * 2);

  k_prep<<<PREP_EXB0 + (2 * EDGES) / 4, 256, 0, stream>>>(
      Rr, Rs, rp_w, re_w1, re_w2, recv, send,
      rpT_h, rpT_l, re1T_h, re1T_l, re2T_h, re2T_l, counts);

  k_pre<<<256, 256, 0, stream>>>(
      a_cur, s_cur, s_delta, ea, recv, send,
      pe_w0, pe_b0, pe_w1, pe_b1, re_w0, re_b0, re_b1, re_b2,
      re1T_h, re1T_l, re2T_h, re2T_l,
      pe, pe_h, pe_l, rel_h, rel_l, counts, bucket);

  const float* esrc = pe;
  const f16* esrc_h = pe_h;
  const f16* esrc_l = pe_l;
  for (int s = 0; s < PSTEP_; ++s) {
    float* dst_f = (s == 1) ? effB   : effA;
    f16*  dst_h  = (s == 1) ? effB_h : effA_h;
    f16*  dst_l  = (s == 1) ? effB_l : effA_l;
    k_erel<<<EDGES / 128, 256, 0, stream>>>(rel_h, rel_l, esrc_h, esrc_l,
                                            recv, send, rpT_h, rpT_l, rp_b, e_rel);
    k_update<<<NODES / 16, 256, 0, stream>>>(
        pe, e_rel, counts, bucket, esrc, pp_w, pp_b, dst_f, dst_h, dst_l,
        s_cur, pr_w0, pr_b0, pr_w1, pr_b1, out, (s == PSTEP_ - 1) ? 1 : 0);
    esrc = dst_f; esrc_h = dst_h; esrc_l = dst_l;
  }
}

// Round 8
// 661.182 us; speedup vs baseline: 1.3648x; 1.0473x over previous
//
#include <hip/hip_runtime.h>
#include <hip/hip_bf16.h>
#include <stdint.h>

#define B_ 2
#define N_ 2048      // 2^11
#define R_ 16384     // 2^14
#define NF_ 128
#define NH_ 3
#define PSTEP_ 3
#define EDGES (B_ * R_)    // 32768
#define NODES (B_ * N_)    // 4096
#define MAXDEG 64
#define PREP_EXB0 1024

typedef _Float16 f16;
typedef _Float16 f16x4 __attribute__((ext_vector_type(4)));
typedef float f32x4 __attribute__((ext_vector_type(4)));

struct GemmLds128 { f16 Ah[128 * 128], Bh[128 * 128]; };   // 64 KB (k_pre relation)
struct GemmLds64  { f16 Ah[64 * 128],  Bh[128 * 128]; };   // 48 KB (k_erel)
struct VecLds {
  float wbuf[64][NF_];          // 32 KB
  float xt[NF_][20];            // 10 KB
  float ht[NF_][20];            // 10 KB
  float w0s[10][NF_];
  float b0s[NF_], b1s[NF_];
  float xs[16][10];
  float w1s[NF_][4];
};
union PreLds { GemmLds128 g; VecLds v; };

// ---------------------------------------------------------------------------
__device__ __forceinline__ void gl16(const f16* g, f16* l) {
  typedef const __attribute__((address_space(1))) uint32_t* gas_t;
  typedef __attribute__((address_space(3))) uint32_t* las_t;
  __builtin_amdgcn_global_load_lds((gas_t)(const void*)g, (las_t)(void*)l, 16, 0, 0);
}

// MMxK=128 x N=128 f16 MFMA block GEMM step (A,B staged in LDS, swizzled).
template<int MM>
__device__ __forceinline__ void mfma_blockT(const f16* Ah, const f16* Bh,
                                            f32x4 (&acc)[MM][2], int lane, int w) {
  const int l16 = lane & 15, l4 = lane >> 4;
  #pragma unroll 1
  for (int kk = 0; kk < 8; ++kk) {
    const int c16 = kk * 2 + (l4 >> 1);
    const int sub = (l4 & 1) * 4;
    f16x4 bh[2];
    #pragma unroll
    for (int nf = 0; nf < 2; ++nf) {
      const int n = w * 32 + nf * 16 + l16;
      bh[nf] = *(const f16x4*)&Bh[n * 128 + ((c16 ^ (n & 7)) * 8) + sub];
    }
    #pragma unroll
    for (int m = 0; m < MM; ++m) {
      const int r = m * 16 + l16;
      const f16x4 ah = *(const f16x4*)&Ah[r * 128 + ((c16 ^ (r & 7)) * 8) + sub];
      #pragma unroll
      for (int nf = 0; nf < 2; ++nf)
        acc[m][nf] = __builtin_amdgcn_mfma_f32_16x16x16f16(ah, bh[nf], acc[m][nf], 0, 0, 0);
    }
  }
}

// relu + f16 frag write back into swizzled LDS A-tile (128-row tile).
__device__ __forceinline__ void frags_to_lds(f32x4 (&acc)[8][2], f16* Ah,
                                             int lane, int w) {
  const int l16 = lane & 15, l4 = lane >> 4;
  #pragma unroll
  for (int m = 0; m < 8; ++m)
    #pragma unroll
    for (int nf = 0; nf < 2; ++nf)
      #pragma unroll
      for (int i = 0; i < 4; ++i) {
        const float v = fmaxf(acc[m][nf][i], 0.f);
        const int row = m * 16 + l4 * 4 + i;
        const int col = w * 32 + nf * 16 + l16;
        Ah[row * 128 + (((col >> 3) ^ (row & 7)) * 8) + (col & 7)] = (f16)v;
      }
}

// ---------------------------------------------------------------------------
// Launch 1: zero CSR counts + weight convert/transpose (f16) + extract.
// ---------------------------------------------------------------------------
__global__ __launch_bounds__(256) void k_prep(
    const float* __restrict__ Rr, const float* __restrict__ Rs,
    const float* __restrict__ rp_w, const float* __restrict__ re_w1,
    const float* __restrict__ re_w2,
    int* __restrict__ recv, int* __restrict__ send,
    f16* __restrict__ rpT_h, f16* __restrict__ re1T_h, f16* __restrict__ re2T_h,
    int* __restrict__ counts) {
  const int bid = blockIdx.x, t = threadIdx.x;
  if (bid < 16) {                          // zero counts (4096 ints)
    counts[bid * 256 + t] = 0;
  } else if (bid < 336) {                  // weight convert (81920 elements)
    const int i = (bid - 16) * 256 + t;
    const int S1 = 384 * 128, S2 = S1 + 128 * 128, S3 = S2 + 128 * 128;
    if (i < S1) {
      const int k = i >> 7, n = i & 127;
      rpT_h[n * 384 + k] = (f16)rp_w[i];
    } else if (i < S2) {
      const int j = i - S1, k = j >> 7, n = j & 127;
      re1T_h[n * 128 + k] = (f16)re_w1[j];
    } else if (i < S3) {
      const int j = i - S2, k = j >> 7, n = j & 127;
      re2T_h[n * 128 + k] = (f16)re_w2[j];
    }
  } else if (bid >= PREP_EXB0) {           // extract: one wave per one-hot row
    const int wid = (bid - PREP_EXB0) * 4 + (t >> 6);
    const int lane = t & 63;
    const bool isR = wid < EDGES;
    const int row = isR ? wid : wid - EDGES;
    const float4* p = reinterpret_cast<const float4*>((isR ? Rr : Rs) + (size_t)row * N_);
    int found = 0;
    #pragma unroll 1
    for (int it = 0; it < N_ / 256; ++it) {
      const float4 v = p[it * 64 + lane];
      const int base = (it * 64 + lane) * 4;
      bool hit = false;
      if (v.x != 0.f) { found = base;     hit = true; }
      if (v.y != 0.f) { found = base + 1; hit = true; }
      if (v.z != 0.f) { found = base + 2; hit = true; }
      if (v.w != 0.f) { found = base + 3; hit = true; }
      if (__any(hit)) break;
    }
    #pragma unroll
    for (int off = 32; off > 0; off >>= 1)
      found = max(found, __shfl_down(found, off, 64));
    if (lane == 0) (isR ? recv : send)[row] = found;
  }
}

// ---------------------------------------------------------------------------
// Launch 2: CSR bucket fill + particle_encode (16 nodes/block) + relation
// L1+L2+L3 fused (128 edges/block).  256 blocks, 2 blocks/CU.
// ---------------------------------------------------------------------------
__global__ __launch_bounds__(256, 2) void k_pre(
    const float* __restrict__ a_cur, const float* __restrict__ s_cur,
    const float* __restrict__ s_delta, const float* __restrict__ ea,
    const int* __restrict__ recv, const int* __restrict__ send,
    const float* __restrict__ pe_w0, const float* __restrict__ pe_b0,
    const float* __restrict__ pe_w1, const float* __restrict__ pe_b1,
    const float* __restrict__ re_w0, const float* __restrict__ re_b0,
    const float* __restrict__ re_b1, const float* __restrict__ re_b2,
    const f16* __restrict__ re1T_h, const f16* __restrict__ re2T_h,
    float* __restrict__ pe, f16* __restrict__ pe_h,
    f16* __restrict__ rel_h,
    int* __restrict__ counts, int* __restrict__ bucket) {
  __shared__ PreLds u;
  __shared__ float xt6[6][128];
  __shared__ float w0s6[6][128];
  __shared__ float sb0[128];

  const int bid = blockIdx.x, t = threadIdx.x;
  const int lane = t & 63, w = t >> 6;
  const int l16 = lane & 15, l4 = lane >> 4;
  const int f = t & 127, g = t >> 7;

  // ---------------- CSR bucket fill -----------------------------------------
  {
    const int e = bid * 128 + t;   // covers 32768 with 256 blocks x 128... no:
  }
  {
    const int e = bid * 256 + t;   // 256 blocks x 256 thr = 65536 > EDGES
    if (e < EDGES) {
      const int gnode = (e >> 14) * N_ + recv[e];
      const int pos = atomicAdd(&counts[gnode], 1);
      if (pos < MAXDEG) bucket[gnode * MAXDEG + pos] = e;
    }
  }

  auto stageB = [&](const f16* gh) {
    #pragma unroll
    for (int rb = 0; rb < 32; rb += 4) {
      const int r0w = w * 32 + rb;
      const int row = r0w + l4;
      const int sc = (l16 ^ (row & 7)) * 8;
      gl16(gh + (size_t)row * 128 + sc, &u.g.Bh[r0w * 128]);
    }
  };

  // ---------------- particle_encode -----------------------------------------
  {
    const int r0 = bid * 16;
    for (int i = t; i < 10 * NF_; i += 256) u.v.w0s[i >> 7][i & 127] = pe_w0[i];
    if (t < NF_) { u.v.b0s[t] = pe_b0[t]; u.v.b1s[t] = pe_b1[t]; }
    for (int i = t; i < 160; i += 256) {
      const int r = i / 10, k = i % 10;
      const int gr = r0 + r, bb = gr >> 11, n = gr & (N_ - 1);
      u.v.xs[r][k] = (k < 9)
          ? s_delta[(((size_t)bb * NH_ + (k / 3)) * N_ + n) * 3 + (k % 3)]
          : a_cur[gr];
    }
    __syncthreads();
    for (int r = g * 8; r < g * 8 + 8; ++r) {
      float a1 = u.v.b0s[f];
      #pragma unroll
      for (int k = 0; k < 10; ++k) a1 = fmaf(u.v.xs[r][k], u.v.w0s[k][f], a1);
      u.v.ht[f][r] = fmaxf(a1, 0.f);
    }
    float acc[8];
    #pragma unroll
    for (int i = 0; i < 8; ++i) acc[i] = u.v.b1s[f];
    for (int h = 0; h < 2; ++h) {
      __syncthreads();
      for (int i = t; i < 64 * NF_; i += 256) u.v.wbuf[i >> 7][i & 127] = pe_w1[h * 64 * NF_ + i];
      __syncthreads();
      for (int k = 0; k < 64; ++k) {
        const float wv = u.v.wbuf[k][f];
        #pragma unroll
        for (int i = 0; i < 2; ++i) {
          const float4 x4 = *reinterpret_cast<const float4*>(&u.v.ht[h * 64 + k][g * 8 + i * 4]);
          acc[i*4+0] = fmaf(x4.x, wv, acc[i*4+0]);
          acc[i*4+1] = fmaf(x4.y, wv, acc[i*4+1]);
          acc[i*4+2] = fmaf(x4.z, wv, acc[i*4+2]);
          acc[i*4+3] = fmaf(x4.w, wv, acc[i*4+3]);
        }
      }
    }
    #pragma unroll
    for (int i = 0; i < 8; ++i) {
      const size_t idx = (size_t)(r0 + g * 8 + i) * NF_ + f;
      const float v = fmaxf(acc[i], 0.f);
      pe[idx] = v;
      pe_h[idx] = (f16)v;
    }
  }
  __syncthreads();

  // ---------------- relation L1+L2+L3 ---------------------------------------
  {
    const int e0 = bid * 128;
    if (t < 128) {
      const int ge = e0 + t, bb = ge >> 14;
      const int rc = recv[ge], sd = send[ge];
      xt6[0][t] = a_cur[(bb << 11) + rc];
      xt6[1][t] = a_cur[(bb << 11) + sd];
      #pragma unroll
      for (int d = 0; d < 3; ++d)
        xt6[2 + d][t] = s_cur[(size_t)((bb << 11) + rc) * 3 + d]
                      - s_cur[(size_t)((bb << 11) + sd) * 3 + d];
      xt6[5][t] = ea[ge];
    }
    stageB(re1T_h);
    for (int i = t; i < 6 * 128; i += 256) w0s6[i >> 7][i & 127] = re_w0[i];
    if (t < 128) sb0[t] = re_b0[t];
    __syncthreads();
    // L1 (K=6) -> h1 in swizzled LDS A-tile
    {
      float wreg[6];
      #pragma unroll
      for (int k = 0; k < 6; ++k) wreg[k] = w0s6[k][f];
      const float b0v = sb0[f];
      for (int r = g * 64; r < g * 64 + 64; ++r) {
        float a1 = b0v;
        #pragma unroll
        for (int k = 0; k < 6; ++k) a1 = fmaf(xt6[k][r], wreg[k], a1);
        a1 = fmaxf(a1, 0.f);
        u.g.Ah[r * 128 + ((((f >> 3)) ^ (r & 7)) * 8) + (f & 7)] = (f16)a1;
      }
    }
    __syncthreads();
    f32x4 acc[8][2];
    {
      const float bv0 = re_b1[w * 32 + l16], bv1 = re_b1[w * 32 + 16 + l16];
      #pragma unroll
      for (int m = 0; m < 8; ++m) {
        acc[m][0] = (f32x4){bv0, bv0, bv0, bv0};
        acc[m][1] = (f32x4){bv1, bv1, bv1, bv1};
      }
    }
    mfma_blockT<8>(u.g.Ah, u.g.Bh, acc, lane, w);
    __syncthreads();
    frags_to_lds(acc, u.g.Ah, lane, w);
    stageB(re2T_h);
    {
      const float bv0 = re_b2[w * 32 + l16], bv1 = re_b2[w * 32 + 16 + l16];
      #pragma unroll
      for (int m = 0; m < 8; ++m) {
        acc[m][0] = (f32x4){bv0, bv0, bv0, bv0};
        acc[m][1] = (f32x4){bv1, bv1, bv1, bv1};
      }
    }
    __syncthreads();
    mfma_blockT<8>(u.g.Ah, u.g.Bh, acc, lane, w);
    __syncthreads();
    frags_to_lds(acc, u.g.Ah, lane, w);
    __syncthreads();
    // copy rel tile (swizzled layout preserved) LDS -> global: 8 f4/half-row
    {
      const int row = t >> 1, hf = t & 1;
      const float4* sA = (const float4*)&u.g.Ah[row * 128 + hf * 64];
      float4* dA = (float4*)&rel_h[(size_t)(e0 + row) * 128 + hf * 64];
      #pragma unroll
      for (int j = 0; j < 8; ++j) dA[j] = sA[j];
    }
  }
}

// ---------------------------------------------------------------------------
// Launch 3/5/7: erel GEMM (K=384, 3 chunks) -> e_rel.  64 edges/block,
// 512 blocks, 48 KB LDS -> 2-3 blocks/CU.
// ---------------------------------------------------------------------------
__global__ __launch_bounds__(256, 2) void k_erel(
    const f16* __restrict__ rel_h, const f16* __restrict__ src_h,
    const int* __restrict__ recv, const int* __restrict__ send,
    const f16* __restrict__ rpT_h,
    const float* __restrict__ rp_b, float* __restrict__ e_rel) {
  __shared__ GemmLds64 u;
  __shared__ int eidx0[64], eidx1[64];
  const int bid = blockIdx.x, t = threadIdx.x;
  const int lane = t & 63, w = t >> 6;
  const int l16 = lane & 15, l4 = lane >> 4;
  const int e0 = bid * 64;
  const int b = bid >> 8;                  // 256 blocks per batch
  if (t < 64) eidx0[t] = recv[e0 + t];
  else if (t < 128) eidx1[t - 64] = send[e0 + t - 64];
  f32x4 acc[4][2];
  {
    const float bv0 = rp_b[w * 32 + l16], bv1 = rp_b[w * 32 + 16 + l16];
    #pragma unroll
    for (int m = 0; m < 4; ++m) {
      acc[m][0] = (f32x4){bv0, bv0, bv0, bv0};
      acc[m][1] = (f32x4){bv1, bv1, bv1, bv1};
    }
  }
  #pragma unroll 1
  for (int ch = 0; ch < 3; ++ch) {
    __syncthreads();
    // stage A: 64 rows x 128 k, each wave 16 rows (4 gl16)
    #pragma unroll
    for (int rb = 0; rb < 16; rb += 4) {
      const int r0w = w * 16 + rb;
      const int row = r0w + l4;
      const int ge = e0 + row;
      if (ch == 0) {
        gl16(rel_h + (size_t)ge * 128 + l16 * 8, &u.Ah[r0w * 128]);
      } else {
        const int node = (ch == 1) ? eidx0[row] : eidx1[row];
        const size_t ao = ((size_t)(b << 11) + node) * 128 + ((l16 ^ (row & 7)) * 8);
        gl16(src_h + ao, &u.Ah[r0w * 128]);
      }
    }
    // stage B: 128 rows, each wave 32 rows (8 gl16)
    #pragma unroll
    for (int rb = 0; rb < 32; rb += 4) {
      const int r0w = w * 32 + rb;
      const int row = r0w + l4;
      const int sc = (l16 ^ (row & 7)) * 8;
      gl16(rpT_h + (size_t)row * 384 + ch * 128 + sc, &u.Bh[r0w * 128]);
    }
    __syncthreads();
    mfma_blockT<4>(u.Ah, u.Bh, acc, lane, w);
  }
  #pragma unroll
  for (int m = 0; m < 4; ++m)
    #pragma unroll
    for (int nf = 0; nf < 2; ++nf)
      #pragma unroll
      for (int i = 0; i < 4; ++i) {
        const float v = fmaxf(acc[m][nf][i], 0.f);
        const int row = e0 + m * 16 + l4 * 4 + i;
        const int col = w * 32 + nf * 16 + l16;
        e_rel[(size_t)row * NF_ + col] = v;
      }
}

// ---------------------------------------------------------------------------
// Launch 4/6/8: gather-agg + effect update MLP (16 nodes/block, K=256).
// final_step!=0: fuse predict.
// ---------------------------------------------------------------------------
__global__ __launch_bounds__(256, 2) void k_update(
    const float* __restrict__ pe, const float* __restrict__ e_rel,
    const int* __restrict__ counts, const int* __restrict__ bucket,
    const float* __restrict__ src_f,
    const float* __restrict__ pp_w, const float* __restrict__ pp_b,
    float* __restrict__ dst_f, f16* __restrict__ dst_h,
    const float* __restrict__ s_cur,
    const float* __restrict__ pr_w0, const float* __restrict__ pr_b0,
    const float* __restrict__ pr_w1, const float* __restrict__ pr_b1,
    float* __restrict__ out, int final_step) {
  __shared__ alignas(16) float wbuf[64][NF_];
  __shared__ alignas(16) float xt[NF_][20];
  __shared__ alignas(16) float ht[NF_][20];
  __shared__ float w1s[NF_][4];
  const int t = threadIdx.x, f = t & 127, g = t >> 7;
  const int r0 = blockIdx.x * 16;
  float acc[8];
  {
    const float bias = pp_b[f];
    #pragma unroll
    for (int i = 0; i < 8; ++i) acc[i] = bias;
  }
  for (int c = 0; c < 2; ++c) {
    __syncthreads();
    {
      const int e = t >> 4, k0 = (t & 15) * 8;
      float s[8];
      if (c == 0) {
        const float* srcp = pe + (size_t)(r0 + e) * NF_ + k0;
        const float4 v0 = *reinterpret_cast<const float4*>(srcp);
        const float4 v1 = *reinterpret_cast<const float4*>(srcp + 4);
        s[0]=v0.x; s[1]=v0.y; s[2]=v0.z; s[3]=v0.w;
        s[4]=v1.x; s[5]=v1.y; s[6]=v1.z; s[7]=v1.w;
      } else {
        #pragma unroll
        for (int i = 0; i < 8; ++i) s[i] = 0.f;
        const int gnode = r0 + e;
        const int cnt = min(counts[gnode], MAXDEG);
        for (int i = 0; i < cnt; ++i) {
          const int ed = bucket[gnode * MAXDEG + i];
          const float4 v0 = *reinterpret_cast<const float4*>(&e_rel[(size_t)ed * NF_ + k0]);
          const float4 v1 = *reinterpret_cast<const float4*>(&e_rel[(size_t)ed * NF_ + k0 + 4]);
          s[0]+=v0.x; s[1]+=v0.y; s[2]+=v0.z; s[3]+=v0.w;
          s[4]+=v1.x; s[5]+=v1.y; s[6]+=v1.z; s[7]+=v1.w;
        }
      }
      #pragma unroll
      for (int i = 0; i < 8; ++i) xt[k0 + i][e] = s[i];
    }
    #pragma unroll 1
    for (int h = 0; h < 2; ++h) {
      __syncthreads();
      for (int i = t; i < 64 * NF_; i += 256)
        wbuf[i >> 7][i & 127] = pp_w[(size_t)(c * NF_ + h * 64) * NF_ + i];
      __syncthreads();
      for (int k = 0; k < 64; ++k) {
        const float wv = wbuf[k][f];
        const int ka = h * 64 + k;
        #pragma unroll
        for (int i = 0; i < 2; ++i) {
          const float4 x4 = *reinterpret_cast<const float4*>(&xt[ka][g * 8 + i * 4]);
          acc[i*4+0] = fmaf(x4.x, wv, acc[i*4+0]);
          acc[i*4+1] = fmaf(x4.y, wv, acc[i*4+1]);
          acc[i*4+2] = fmaf(x4.z, wv, acc[i*4+2]);
          acc[i*4+3] = fmaf(x4.w, wv, acc[i*4+3]);
        }
      }
    }
  }
  if (!final_step) {
    #pragma unroll
    for (int i = 0; i < 8; ++i) {
      const size_t idx = (size_t)(r0 + g * 8 + i) * NF_ + f;
      const float v = fmaxf(acc[i] + src_f[idx], 0.f);
      dst_f[idx] = v;
      dst_h[idx] = (f16)v;
    }
    return;
  }
  // ---------------- fused predict (final step) ------------------------------
  __syncthreads();
  #pragma unroll
  for (int i = 0; i < 8; ++i) {
    const size_t idx = (size_t)(r0 + g * 8 + i) * NF_ + f;
    xt[f][g * 8 + i] = fmaxf(acc[i] + src_f[idx], 0.f);
  }
  for (int i = t; i < NF_ * 3; i += 256) w1s[i / 3][i % 3] = pr_w1[i];
  {
    const float bias = pr_b0[f];
    #pragma unroll
    for (int i = 0; i < 8; ++i) acc[i] = bias;
  }
  for (int h = 0; h < 2; ++h) {
    __syncthreads();
    for (int i = t; i < 64 * NF_; i += 256) wbuf[i >> 7][i & 127] = pr_w0[h * 64 * NF_ + i];
    __syncthreads();
    for (int k = 0; k < 64; ++k) {
      const float wv = wbuf[k][f];
      const int ka = h * 64 + k;
      #pragma unroll
      for (int i = 0; i < 2; ++i) {
        const float4 x4 = *reinterpret_cast<const float4*>(&xt[ka][g * 8 + i * 4]);
        acc[i*4+0] = fmaf(x4.x, wv, acc[i*4+0]);
        acc[i*4+1] = fmaf(x4.y, wv, acc[i*4+1]);
        acc[i*4+2] = fmaf(x4.z, wv, acc[i*4+2]);
        acc[i*4+3] = fmaf(x4.w, wv, acc[i*4+3]);
      }
    }
  }
  #pragma unroll
  for (int i = 0; i < 8; ++i) ht[f][g * 8 + i] = fmaxf(acc[i], 0.f);
  __syncthreads();
  if (t < 48) {
    const int r = t / 3, d = t % 3;
    float a2 = pr_b1[d];
    for (int k = 0; k < NF_; ++k) a2 = fmaf(ht[k][r], w1s[k][d], a2);
    const int gr = r0 + r;
    out[(size_t)gr * 3 + d] = a2 + s_cur[(size_t)gr * 3 + d];
  }
}

// ---------------------------------------------------------------------------
extern "C" void kernel_launch(void* const* d_in, const int* in_sizes, int n_in,
                              void* d_out, int out_size, void* d_ws, size_t ws_size,
                              hipStream_t stream) {
  (void)in_sizes; (void)n_in; (void)out_size; (void)ws_size;
  const float* a_cur   = (const float*)d_in[0];
  const float* s_cur   = (const float*)d_in[1];
  const float* s_delta = (const float*)d_in[2];
  const float* Rr      = (const float*)d_in[3];
  const float* Rs      = (const float*)d_in[4];
  const float* ea      = (const float*)d_in[5];
  const float* pe_w0 = (const float*)d_in[6];
  const float* pe_b0 = (const float*)d_in[7];
  const float* pe_w1 = (const float*)d_in[8];
  const float* pe_b1 = (const float*)d_in[9];
  const float* re_w0 = (const float*)d_in[10];
  const float* re_b0 = (const float*)d_in[11];
  const float* re_w1 = (const float*)d_in[12];
  const float* re_b1 = (const float*)d_in[13];
  const float* re_w2 = (const float*)d_in[14];
  const float* re_b2 = (const float*)d_in[15];
  const float* rp_w  = (const float*)d_in[16];
  const float* rp_b  = (const float*)d_in[17];
  const float* pp_w  = (const float*)d_in[18];
  const float* pp_b  = (const float*)d_in[19];
  const float* pr_w0 = (const float*)d_in[20];
  const float* pr_b0 = (const float*)d_in[21];
  const float* pr_w1 = (const float*)d_in[22];
  const float* pr_b1 = (const float*)d_in[23];
  float* out = (float*)d_out;

  uint8_t* wp = (uint8_t*)d_ws;
  auto alloc = [&](size_t bytes) {
    void* p = (void*)wp;
    wp += (bytes + 255) & ~(size_t)255;
    return p;
  };
  int* recv   = (int*)alloc(EDGES * 4);
  int* send   = (int*)alloc(EDGES * 4);
  int* counts = (int*)alloc(NODES * 4);
  int* bucket = (int*)alloc((size_t)NODES * MAXDEG * 4);
  float* pe   = (float*)alloc((size_t)NODES * NF_ * 4);
  f16* pe_h   = (f16*)alloc((size_t)NODES * NF_ * 2);
  float* effA = (float*)alloc((size_t)NODES * NF_ * 4);
  f16* effA_h = (f16*)alloc((size_t)NODES * NF_ * 2);
  float* effB = (float*)alloc((size_t)NODES * NF_ * 4);
  f16* effB_h = (f16*)alloc((size_t)NODES * NF_ * 2);
  float* e_rel = (float*)alloc((size_t)EDGES * NF_ * 4);
  f16* rel_h  = (f16*)alloc((size_t)EDGES * NF_ * 2);
  f16* rpT_h  = (f16*)alloc(128 * 384 * 2);
  f16* re1T_h = (f16*)alloc(128 * 128 * 2);
  f16* re2T_h = (f16*)alloc(128 * 128 * 2);

  k_prep<<<PREP_EXB0 + (2 * EDGES) / 4, 256, 0, stream>>>(
      Rr, Rs, rp_w, re_w1, re_w2, recv, send,
      rpT_h, re1T_h, re2T_h, counts);

  k_pre<<<256, 256, 0, stream>>>(
      a_cur, s_cur, s_delta, ea, recv, send,
      pe_w0, pe_b0, pe_w1, pe_b1, re_w0, re_b0, re_b1, re_b2,
      re1T_h, re2T_h, pe, pe_h, rel_h, counts, bucket);

  const float* esrc = pe;
  const f16* esrc_h = pe_h;
  for (int s = 0; s < PSTEP_; ++s) {
    float* dst_f = (s == 1) ? effB   : effA;
    f16*  dst_h  = (s == 1) ? effB_h : effA_h;
    k_erel<<<EDGES / 64, 256, 0, stream>>>(rel_h, esrc_h, recv, send,
                                           rpT_h, rp_b, e_rel);
    k_update<<<NODES / 16, 256, 0, stream>>>(
        pe, e_rel, counts, bucket, esrc, pp_w, pp_b, dst_f, dst_h,
        s_cur, pr_w0, pr_b0, pr_w1, pr_b1, out, (s == PSTEP_ - 1) ? 1 : 0);
    esrc = dst_f; esrc_h = dst_h;
  }
}

// Round 9
// 660.730 us; speedup vs baseline: 1.3658x; 1.0007x over previous
//
#include <hip/hip_runtime.h>
#include <hip/hip_bf16.h>
#include <stdint.h>

#define B_ 2
#define N_ 2048      // 2^11
#define R_ 16384     // 2^14
#define NF_ 128
#define NH_ 3
#define PSTEP_ 3
#define EDGES (B_ * R_)    // 32768
#define NODES (B_ * N_)    // 4096
#define MAXDEG 64
#define PREP_EXB0 1024

typedef _Float16 f16;
typedef _Float16 f16x4 __attribute__((ext_vector_type(4)));
typedef _Float16 f16x8 __attribute__((ext_vector_type(8)));
typedef float f32x4 __attribute__((ext_vector_type(4)));

struct GemmLds128 { f16 Ah[128 * 128], Bh[128 * 128]; };   // 64 KB (k_pre relation)
struct GemmLds64  { f16 Ah[64 * 128],  Bh[128 * 128]; };   // 48 KB (k_erel)
struct VecLds {
  float wbuf[64][NF_];          // 32 KB
  float xt[NF_][20];            // 10 KB
  float ht[NF_][20];            // 10 KB
  float w0s[10][NF_];
  float b0s[NF_], b1s[NF_];
  float xs[16][10];
  float w1s[NF_][4];
};
union PreLds { GemmLds128 g; VecLds v; };

// ---------------------------------------------------------------------------
__device__ __forceinline__ void gl16(const f16* g, f16* l) {
  typedef const __attribute__((address_space(1))) uint32_t* gas_t;
  typedef __attribute__((address_space(3))) uint32_t* las_t;
  __builtin_amdgcn_global_load_lds((gas_t)(const void*)g, (las_t)(void*)l, 16, 0, 0);
}

// MMx16 rows x 128 cols x K=128 f16 MFMA block GEMM (A,B in LDS, swizzled).
template<int MM>
__device__ __forceinline__ void mfma_blockT(const f16* Ah, const f16* Bh,
                                            f32x4 (&acc)[MM][2], int lane, int w) {
  const int l16 = lane & 15, l4 = lane >> 4;
  #pragma unroll 1
  for (int kk = 0; kk < 8; ++kk) {
    const int c16 = kk * 2 + (l4 >> 1);
    const int sub = (l4 & 1) * 4;
    f16x4 bh[2];
    #pragma unroll
    for (int nf = 0; nf < 2; ++nf) {
      const int n = w * 32 + nf * 16 + l16;
      bh[nf] = *(const f16x4*)&Bh[n * 128 + ((c16 ^ (n & 7)) * 8) + sub];
    }
    #pragma unroll
    for (int m = 0; m < MM; ++m) {
      const int r = m * 16 + l16;
      const f16x4 ah = *(const f16x4*)&Ah[r * 128 + ((c16 ^ (r & 7)) * 8) + sub];
      #pragma unroll
      for (int nf = 0; nf < 2; ++nf)
        acc[m][nf] = __builtin_amdgcn_mfma_f32_16x16x16f16(ah, bh[nf], acc[m][nf], 0, 0, 0);
    }
  }
}

// relu + f16 frag write back into swizzled LDS A-tile (128-row tile).
__device__ __forceinline__ void frags_to_lds(f32x4 (&acc)[8][2], f16* Ah,
                                             int lane, int w) {
  const int l16 = lane & 15, l4 = lane >> 4;
  #pragma unroll
  for (int m = 0; m < 8; ++m)
    #pragma unroll
    for (int nf = 0; nf < 2; ++nf)
      #pragma unroll
      for (int i = 0; i < 4; ++i) {
        const float v = fmaxf(acc[m][nf][i], 0.f);
        const int row = m * 16 + l4 * 4 + i;
        const int col = w * 32 + nf * 16 + l16;
        Ah[row * 128 + (((col >> 3) ^ (row & 7)) * 8) + (col & 7)] = (f16)v;
      }
}

// ---------------------------------------------------------------------------
// Launch 1: zero CSR counts + weight convert/transpose (f16) + extract.
// ---------------------------------------------------------------------------
__global__ __launch_bounds__(256) void k_prep(
    const float* __restrict__ Rr, const float* __restrict__ Rs,
    const float* __restrict__ rp_w, const float* __restrict__ re_w1,
    const float* __restrict__ re_w2,
    int* __restrict__ recv, int* __restrict__ send,
    f16* __restrict__ rpT_h, f16* __restrict__ re1T_h, f16* __restrict__ re2T_h,
    int* __restrict__ counts) {
  const int bid = blockIdx.x, t = threadIdx.x;
  if (bid < 16) {                          // zero counts (4096 ints)
    counts[bid * 256 + t] = 0;
  } else if (bid < 336) {                  // weight convert (81920 elements)
    const int i = (bid - 16) * 256 + t;
    const int S1 = 384 * 128, S2 = S1 + 128 * 128, S3 = S2 + 128 * 128;
    if (i < S1) {
      const int k = i >> 7, n = i & 127;
      rpT_h[n * 384 + k] = (f16)rp_w[i];
    } else if (i < S2) {
      const int j = i - S1, k = j >> 7, n = j & 127;
      re1T_h[n * 128 + k] = (f16)re_w1[j];
    } else if (i < S3) {
      const int j = i - S2, k = j >> 7, n = j & 127;
      re2T_h[n * 128 + k] = (f16)re_w2[j];
    }
  } else if (bid >= PREP_EXB0) {           // extract: one wave per one-hot row
    const int wid = (bid - PREP_EXB0) * 4 + (t >> 6);
    const int lane = t & 63;
    const bool isR = wid < EDGES;
    const int row = isR ? wid : wid - EDGES;
    const float4* p = reinterpret_cast<const float4*>((isR ? Rr : Rs) + (size_t)row * N_);
    int found = 0;
    #pragma unroll 1
    for (int it = 0; it < N_ / 256; ++it) {
      const float4 v = p[it * 64 + lane];
      const int base = (it * 64 + lane) * 4;
      bool hit = false;
      if (v.x != 0.f) { found = base;     hit = true; }
      if (v.y != 0.f) { found = base + 1; hit = true; }
      if (v.z != 0.f) { found = base + 2; hit = true; }
      if (v.w != 0.f) { found = base + 3; hit = true; }
      if (__any(hit)) break;
    }
    #pragma unroll
    for (int off = 32; off > 0; off >>= 1)
      found = max(found, __shfl_down(found, off, 64));
    if (lane == 0) (isR ? recv : send)[row] = found;
  }
}

// ---------------------------------------------------------------------------
// Launch 2: CSR bucket fill + particle_encode (16 nodes/block) + relation
// L1+L2+L3 fused (128 edges/block).  256 blocks, 2 blocks/CU.
// ---------------------------------------------------------------------------
__global__ __launch_bounds__(256, 2) void k_pre(
    const float* __restrict__ a_cur, const float* __restrict__ s_cur,
    const float* __restrict__ s_delta, const float* __restrict__ ea,
    const int* __restrict__ recv, const int* __restrict__ send,
    const float* __restrict__ pe_w0, const float* __restrict__ pe_b0,
    const float* __restrict__ pe_w1, const float* __restrict__ pe_b1,
    const float* __restrict__ re_w0, const float* __restrict__ re_b0,
    const float* __restrict__ re_b1, const float* __restrict__ re_b2,
    const f16* __restrict__ re1T_h, const f16* __restrict__ re2T_h,
    float* __restrict__ pe, f16* __restrict__ pe_h,
    f16* __restrict__ rel_h,
    int* __restrict__ counts, int* __restrict__ bucket) {
  __shared__ PreLds u;
  __shared__ float xt6[6][128];
  __shared__ float w0s6[6][128];
  __shared__ float sb0[128];

  const int bid = blockIdx.x, t = threadIdx.x;
  const int lane = t & 63, w = t >> 6;
  const int l16 = lane & 15, l4 = lane >> 4;
  const int f = t & 127, g = t >> 7;

  // ---------------- CSR bucket fill -----------------------------------------
  {
    const int e = bid * 256 + t;   // wait-free cover: only e < EDGES act
    if (e < EDGES) {
      const int gnode = (e >> 14) * N_ + recv[e];
      const int pos = atomicAdd(&counts[gnode], 1);
      if (pos < MAXDEG) bucket[gnode * MAXDEG + pos] = e;
    }
  }

  auto stageB = [&](const f16* gh) {
    #pragma unroll
    for (int rb = 0; rb < 32; rb += 4) {
      const int r0w = w * 32 + rb;
      const int row = r0w + l4;
      const int sc = (l16 ^ (row & 7)) * 8;
      gl16(gh + (size_t)row * 128 + sc, &u.g.Bh[r0w * 128]);
    }
  };

  // ---------------- particle_encode -----------------------------------------
  {
    const int r0 = bid * 16;
    for (int i = t; i < 10 * NF_; i += 256) u.v.w0s[i >> 7][i & 127] = pe_w0[i];
    if (t < NF_) { u.v.b0s[t] = pe_b0[t]; u.v.b1s[t] = pe_b1[t]; }
    for (int i = t; i < 160; i += 256) {
      const int r = i / 10, k = i % 10;
      const int gr = r0 + r, bb = gr >> 11, n = gr & (N_ - 1);
      u.v.xs[r][k] = (k < 9)
          ? s_delta[(((size_t)bb * NH_ + (k / 3)) * N_ + n) * 3 + (k % 3)]
          : a_cur[gr];
    }
    __syncthreads();
    for (int r = g * 8; r < g * 8 + 8; ++r) {
      float a1 = u.v.b0s[f];
      #pragma unroll
      for (int k = 0; k < 10; ++k) a1 = fmaf(u.v.xs[r][k], u.v.w0s[k][f], a1);
      u.v.ht[f][r] = fmaxf(a1, 0.f);
    }
    float acc[8];
    #pragma unroll
    for (int i = 0; i < 8; ++i) acc[i] = u.v.b1s[f];
    for (int h = 0; h < 2; ++h) {
      __syncthreads();
      for (int i = t; i < 64 * NF_; i += 256) u.v.wbuf[i >> 7][i & 127] = pe_w1[h * 64 * NF_ + i];
      __syncthreads();
      for (int k = 0; k < 64; ++k) {
        const float wv = u.v.wbuf[k][f];
        #pragma unroll
        for (int i = 0; i < 2; ++i) {
          const float4 x4 = *reinterpret_cast<const float4*>(&u.v.ht[h * 64 + k][g * 8 + i * 4]);
          acc[i*4+0] = fmaf(x4.x, wv, acc[i*4+0]);
          acc[i*4+1] = fmaf(x4.y, wv, acc[i*4+1]);
          acc[i*4+2] = fmaf(x4.z, wv, acc[i*4+2]);
          acc[i*4+3] = fmaf(x4.w, wv, acc[i*4+3]);
        }
      }
    }
    #pragma unroll
    for (int i = 0; i < 8; ++i) {
      const size_t idx = (size_t)(r0 + g * 8 + i) * NF_ + f;
      const float v = fmaxf(acc[i], 0.f);
      pe[idx] = v;
      pe_h[idx] = (f16)v;
    }
  }
  __syncthreads();

  // ---------------- relation L1+L2+L3 ---------------------------------------
  {
    const int e0 = bid * 128;
    if (t < 128) {
      const int ge = e0 + t, bb = ge >> 14;
      const int rc = recv[ge], sd = send[ge];
      xt6[0][t] = a_cur[(bb << 11) + rc];
      xt6[1][t] = a_cur[(bb << 11) + sd];
      #pragma unroll
      for (int d = 0; d < 3; ++d)
        xt6[2 + d][t] = s_cur[(size_t)((bb << 11) + rc) * 3 + d]
                      - s_cur[(size_t)((bb << 11) + sd) * 3 + d];
      xt6[5][t] = ea[ge];
    }
    stageB(re1T_h);
    for (int i = t; i < 6 * 128; i += 256) w0s6[i >> 7][i & 127] = re_w0[i];
    if (t < 128) sb0[t] = re_b0[t];
    __syncthreads();
    // L1 (K=6) -> h1 in swizzled LDS A-tile
    {
      float wreg[6];
      #pragma unroll
      for (int k = 0; k < 6; ++k) wreg[k] = w0s6[k][f];
      const float b0v = sb0[f];
      for (int r = g * 64; r < g * 64 + 64; ++r) {
        float a1 = b0v;
        #pragma unroll
        for (int k = 0; k < 6; ++k) a1 = fmaf(xt6[k][r], wreg[k], a1);
        a1 = fmaxf(a1, 0.f);
        u.g.Ah[r * 128 + ((((f >> 3)) ^ (r & 7)) * 8) + (f & 7)] = (f16)a1;
      }
    }
    __syncthreads();
    f32x4 acc[8][2];
    {
      const float bv0 = re_b1[w * 32 + l16], bv1 = re_b1[w * 32 + 16 + l16];
      #pragma unroll
      for (int m = 0; m < 8; ++m) {
        acc[m][0] = (f32x4){bv0, bv0, bv0, bv0};
        acc[m][1] = (f32x4){bv1, bv1, bv1, bv1};
      }
    }
    mfma_blockT<8>(u.g.Ah, u.g.Bh, acc, lane, w);
    __syncthreads();
    frags_to_lds(acc, u.g.Ah, lane, w);
    stageB(re2T_h);
    {
      const float bv0 = re_b2[w * 32 + l16], bv1 = re_b2[w * 32 + 16 + l16];
      #pragma unroll
      for (int m = 0; m < 8; ++m) {
        acc[m][0] = (f32x4){bv0, bv0, bv0, bv0};
        acc[m][1] = (f32x4){bv1, bv1, bv1, bv1};
      }
    }
    __syncthreads();
    mfma_blockT<8>(u.g.Ah, u.g.Bh, acc, lane, w);
    __syncthreads();
    frags_to_lds(acc, u.g.Ah, lane, w);
    __syncthreads();
    // copy rel tile (swizzled layout preserved) LDS -> global: 8 f4/half-row
    {
      const int row = t >> 1, hf = t & 1;
      const float4* sA = (const float4*)&u.g.Ah[row * 128 + hf * 64];
      float4* dA = (float4*)&rel_h[(size_t)(e0 + row) * 128 + hf * 64];
      #pragma unroll
      for (int j = 0; j < 8; ++j) dA[j] = sA[j];
    }
  }
}

// ---------------------------------------------------------------------------
// Launch 3/5/7: erel GEMM (K=384, 3 chunks) -> e_rel (f16).  64 edges/block.
// ---------------------------------------------------------------------------
__global__ __launch_bounds__(256, 2) void k_erel(
    const f16* __restrict__ rel_h, const f16* __restrict__ src_h,
    const int* __restrict__ recv, const int* __restrict__ send,
    const f16* __restrict__ rpT_h,
    const float* __restrict__ rp_b, f16* __restrict__ e_rel) {
  __shared__ GemmLds64 u;
  __shared__ int eidx0[64], eidx1[64];
  const int bid = blockIdx.x, t = threadIdx.x;
  const int lane = t & 63, w = t >> 6;
  const int l16 = lane & 15, l4 = lane >> 4;
  const int e0 = bid * 64;
  const int b = bid >> 8;                  // 256 blocks per batch
  if (t < 64) eidx0[t] = recv[e0 + t];
  else if (t < 128) eidx1[t - 64] = send[e0 + t - 64];
  f32x4 acc[4][2];
  {
    const float bv0 = rp_b[w * 32 + l16], bv1 = rp_b[w * 32 + 16 + l16];
    #pragma unroll
    for (int m = 0; m < 4; ++m) {
      acc[m][0] = (f32x4){bv0, bv0, bv0, bv0};
      acc[m][1] = (f32x4){bv1, bv1, bv1, bv1};
    }
  }
  #pragma unroll 1
  for (int ch = 0; ch < 3; ++ch) {
    __syncthreads();
    // stage A: 64 rows x 128 k, each wave 16 rows (4 gl16)
    #pragma unroll
    for (int rb = 0; rb < 16; rb += 4) {
      const int r0w = w * 16 + rb;
      const int row = r0w + l4;
      const int ge = e0 + row;
      if (ch == 0) {
        gl16(rel_h + (size_t)ge * 128 + l16 * 8, &u.Ah[r0w * 128]);
      } else {
        const int node = (ch == 1) ? eidx0[row] : eidx1[row];
        const size_t ao = ((size_t)(b << 11) + node) * 128 + ((l16 ^ (row & 7)) * 8);
        gl16(src_h + ao, &u.Ah[r0w * 128]);
      }
    }
    // stage B: 128 rows, each wave 32 rows (8 gl16)
    #pragma unroll
    for (int rb = 0; rb < 32; rb += 4) {
      const int r0w = w * 32 + rb;
      const int row = r0w + l4;
      const int sc = (l16 ^ (row & 7)) * 8;
      gl16(rpT_h + (size_t)row * 384 + ch * 128 + sc, &u.Bh[r0w * 128]);
    }
    __syncthreads();
    mfma_blockT<4>(u.Ah, u.Bh, acc, lane, w);
  }
  #pragma unroll
  for (int m = 0; m < 4; ++m)
    #pragma unroll
    for (int nf = 0; nf < 2; ++nf)
      #pragma unroll
      for (int i = 0; i < 4; ++i) {
        const float v = fmaxf(acc[m][nf][i], 0.f);
        const int row = e0 + m * 16 + l4 * 4 + i;
        const int col = w * 32 + nf * 16 + l16;
        e_rel[(size_t)row * NF_ + col] = (f16)v;
      }
}

// ---------------------------------------------------------------------------
// Launch 4/6/8: gather-agg (f16 e_rel, f32 sum) + update MLP (16 nodes/block).
// final_step!=0: fuse predict.
// ---------------------------------------------------------------------------
__global__ __launch_bounds__(256, 2) void k_update(
    const float* __restrict__ pe, const f16* __restrict__ e_rel,
    const int* __restrict__ counts, const int* __restrict__ bucket,
    const float* __restrict__ src_f,
    const float* __restrict__ pp_w, const float* __restrict__ pp_b,
    float* __restrict__ dst_f, f16* __restrict__ dst_h,
    const float* __restrict__ s_cur,
    const float* __restrict__ pr_w0, const float* __restrict__ pr_b0,
    const float* __restrict__ pr_w1, const float* __restrict__ pr_b1,
    float* __restrict__ out, int final_step) {
  __shared__ alignas(16) float wbuf[64][NF_];
  __shared__ alignas(16) float xt[NF_][20];
  __shared__ alignas(16) float ht[NF_][20];
  __shared__ float w1s[NF_][4];
  const int t = threadIdx.x, f = t & 127, g = t >> 7;
  const int r0 = blockIdx.x * 16;
  float acc[8];
  {
    const float bias = pp_b[f];
    #pragma unroll
    for (int i = 0; i < 8; ++i) acc[i] = bias;
  }
  for (int c = 0; c < 2; ++c) {
    __syncthreads();
    {
      const int e = t >> 4, k0 = (t & 15) * 8;
      float s[8];
      if (c == 0) {
        const float* srcp = pe + (size_t)(r0 + e) * NF_ + k0;
        const float4 v0 = *reinterpret_cast<const float4*>(srcp);
        const float4 v1 = *reinterpret_cast<const float4*>(srcp + 4);
        s[0]=v0.x; s[1]=v0.y; s[2]=v0.z; s[3]=v0.w;
        s[4]=v1.x; s[5]=v1.y; s[6]=v1.z; s[7]=v1.w;
      } else {
        #pragma unroll
        for (int i = 0; i < 8; ++i) s[i] = 0.f;
        const int gnode = r0 + e;
        const int cnt = min(counts[gnode], MAXDEG);
        for (int i = 0; i < cnt; ++i) {
          const int ed = bucket[gnode * MAXDEG + i];
          const f16x8 v = *reinterpret_cast<const f16x8*>(&e_rel[(size_t)ed * NF_ + k0]);
          #pragma unroll
          for (int j = 0; j < 8; ++j) s[j] += (float)v[j];
        }
      }
      #pragma unroll
      for (int i = 0; i < 8; ++i) xt[k0 + i][e] = s[i];
    }
    #pragma unroll 1
    for (int h = 0; h < 2; ++h) {
      __syncthreads();
      for (int i = t; i < 64 * NF_; i += 256)
        wbuf[i >> 7][i & 127] = pp_w[(size_t)(c * NF_ + h * 64) * NF_ + i];
      __syncthreads();
      for (int k = 0; k < 64; ++k) {
        const float wv = wbuf[k][f];
        const int ka = h * 64 + k;
        #pragma unroll
        for (int i = 0; i < 2; ++i) {
          const float4 x4 = *reinterpret_cast<const float4*>(&xt[ka][g * 8 + i * 4]);
          acc[i*4+0] = fmaf(x4.x, wv, acc[i*4+0]);
          acc[i*4+1] = fmaf(x4.y, wv, acc[i*4+1]);
          acc[i*4+2] = fmaf(x4.z, wv, acc[i*4+2]);
          acc[i*4+3] = fmaf(x4.w, wv, acc[i*4+3]);
        }
      }
    }
  }
  if (!final_step) {
    #pragma unroll
    for (int i = 0; i < 8; ++i) {
      const size_t idx = (size_t)(r0 + g * 8 + i) * NF_ + f;
      const float v = fmaxf(acc[i] + src_f[idx], 0.f);
      dst_f[idx] = v;
      dst_h[idx] = (f16)v;
    }
    return;
  }
  // ---------------- fused predict (final step) ------------------------------
  __syncthreads();
  #pragma unroll
  for (int i = 0; i < 8; ++i) {
    const size_t idx = (size_t)(r0 + g * 8 + i) * NF_ + f;
    xt[f][g * 8 + i] = fmaxf(acc[i] + src_f[idx], 0.f);
  }
  for (int i = t; i < NF_ * 3; i += 256) w1s[i / 3][i % 3] = pr_w1[i];
  {
    const float bias = pr_b0[f];
    #pragma unroll
    for (int i = 0; i < 8; ++i) acc[i] = bias;
  }
  for (int h = 0; h < 2; ++h) {
    __syncthreads();
    for (int i = t; i < 64 * NF_; i += 256) wbuf[i >> 7][i & 127] = pr_w0[h * 64 * NF_ + i];
    __syncthreads();
    for (int k = 0; k < 64; ++k) {
      const float wv = wbuf[k][f];
      const int ka = h * 64 + k;
      #pragma unroll
      for (int i = 0; i < 2; ++i) {
        const float4 x4 = *reinterpret_cast<const float4*>(&xt[ka][g * 8 + i * 4]);
        acc[i*4+0] = fmaf(x4.x, wv, acc[i*4+0]);
        acc[i*4+1] = fmaf(x4.y, wv, acc[i*4+1]);
        acc[i*4+2] = fmaf(x4.z, wv, acc[i*4+2]);
        acc[i*4+3] = fmaf(x4.w, wv, acc[i*4+3]);
      }
    }
  }
  #pragma unroll
  for (int i = 0; i < 8; ++i) ht[f][g * 8 + i] = fmaxf(acc[i], 0.f);
  __syncthreads();
  if (t < 48) {
    const int r = t / 3, d = t % 3;
    float a2 = pr_b1[d];
    for (int k = 0; k < NF_; ++k) a2 = fmaf(ht[k][r], w1s[k][d], a2);
    const int gr = r0 + r;
    out[(size_t)gr * 3 + d] = a2 + s_cur[(size_t)gr * 3 + d];
  }
}

// ---------------------------------------------------------------------------
extern "C" void kernel_launch(void* const* d_in, const int* in_sizes, int n_in,
                              void* d_out, int out_size, void* d_ws, size_t ws_size,
                              hipStream_t stream) {
  (void)in_sizes; (void)n_in; (void)out_size; (void)ws_size;
  const float* a_cur   = (const float*)d_in[0];
  const float* s_cur   = (const float*)d_in[1];
  const float* s_delta = (const float*)d_in[2];
  const float* Rr      = (const float*)d_in[3];
  const float* Rs      = (const float*)d_in[4];
  const float* ea      = (const float*)d_in[5];
  const float* pe_w0 = (const float*)d_in[6];
  const float* pe_b0 = (const float*)d_in[7];
  const float* pe_w1 = (const float*)d_in[8];
  const float* pe_b1 = (const float*)d_in[9];
  const float* re_w0 = (const float*)d_in[10];
  const float* re_b0 = (const float*)d_in[11];
  const float* re_w1 = (const float*)d_in[12];
  const float* re_b1 = (const float*)d_in[13];
  const float* re_w2 = (const float*)d_in[14];
  const float* re_b2 = (const float*)d_in[15];
  const float* rp_w  = (const float*)d_in[16];
  const float* rp_b  = (const float*)d_in[17];
  const float* pp_w  = (const float*)d_in[18];
  const float* pp_b  = (const float*)d_in[19];
  const float* pr_w0 = (const float*)d_in[20];
  const float* pr_b0 = (const float*)d_in[21];
  const float* pr_w1 = (const float*)d_in[22];
  const float* pr_b1 = (const float*)d_in[23];
  float* out = (float*)d_out;

  uint8_t* wp = (uint8_t*)d_ws;
  auto alloc = [&](size_t bytes) {
    void* p = (void*)wp;
    wp += (bytes + 255) & ~(size_t)255;
    return p;
  };
  int* recv   = (int*)alloc(EDGES * 4);
  int* send   = (int*)alloc(EDGES * 4);
  int* counts = (int*)alloc(NODES * 4);
  int* bucket = (int*)alloc((size_t)NODES * MAXDEG * 4);
  float* pe   = (float*)alloc((size_t)NODES * NF_ * 4);
  f16* pe_h   = (f16*)alloc((size_t)NODES * NF_ * 2);
  float* effA = (float*)alloc((size_t)NODES * NF_ * 4);
  f16* effA_h = (f16*)alloc((size_t)NODES * NF_ * 2);
  float* effB = (float*)alloc((size_t)NODES * NF_ * 4);
  f16* effB_h = (f16*)alloc((size_t)NODES * NF_ * 2);
  f16* e_rel  = (f16*)alloc((size_t)EDGES * NF_ * 2);
  f16* rel_h  = (f16*)alloc((size_t)EDGES * NF_ * 2);
  f16* rpT_h  = (f16*)alloc(128 * 384 * 2);
  f16* re1T_h = (f16*)alloc(128 * 128 * 2);
  f16* re2T_h = (f16*)alloc(128 * 128 * 2);

  k_prep<<<PREP_EXB0 + (2 * EDGES) / 4, 256, 0, stream>>>(
      Rr, Rs, rp_w, re_w1, re_w2, recv, send,
      rpT_h, re1T_h, re2T_h, counts);

  k_pre<<<256, 256, 0, stream>>>(
      a_cur, s_cur, s_delta, ea, recv, send,
      pe_w0, pe_b0, pe_w1, pe_b1, re_w0, re_b0, re_b1, re_b2,
      re1T_h, re2T_h, pe, pe_h, rel_h, counts, bucket);

  const float* esrc = pe;
  const f16* esrc_h = pe_h;
  for (int s = 0; s < PSTEP_; ++s) {
    float* dst_f = (s == 1) ? effB   : effA;
    f16*  dst_h  = (s == 1) ? effB_h : effA_h;
    k_erel<<<EDGES / 64, 256, 0, stream>>>(rel_h, esrc_h, recv, send,
                                           rpT_h, rp_b, e_rel);
    k_update<<<NODES / 16, 256, 0, stream>>>(
        pe, e_rel, counts, bucket, esrc, pp_w, pp_b, dst_f, dst_h,
        s_cur, pr_w0, pr_b0, pr_w1, pr_b1, out, (s == PSTEP_ - 1) ? 1 : 0);
    esrc = dst_f; esrc_h = dst_h;
  }
}